// Round 8
// baseline (2130.846 us; speedup 1.0000x reference)
//
#include <hip/hip_runtime.h>

constexpr int NN = 500000;
constexpr int NE = 16000000;
constexpr int BN = 512;                       // dst nodes per bucket
constexpr int NBUCK = (NN + BN - 1) / BN;     // 977
constexpr int NSLICE = 8;                     // src slices of 65536 nodes
constexpr int NKEY = NSLICE * BN;             // 4096 sort bins per bucket
constexpr int CAPA = 17408;                   // per-bucket cap: mean 16384, +8 sigma
constexpr int TILE_A = 16384;                 // edges per pass-A tile (LDS-staged)
constexpr int NTILE_A = (NE + TILE_A - 1) / TILE_A; // 977
constexpr int NB_NODE = (NN + 255) / 256;     // 1954

typedef int int4v __attribute__((ext_vector_type(4)));

// ---------------- bf16 helpers ----------------
__device__ __forceinline__ unsigned bfr(float x) {   // fp32 -> bf16 bits (RNE)
    unsigned u = __float_as_uint(x);
    u += 0x7fffu + ((u >> 16) & 1u);
    return u >> 16;
}
__device__ __forceinline__ float bfl(unsigned u) { return __uint_as_float(u << 16); }
__device__ __forceinline__ float bfh(unsigned u) { return __uint_as_float(u & 0xffff0000u); }

// ---------------- pass A: LDS counting sort per tile, coalesced bucket write-out ----
// R1: scattered 4B stores -> 392 MB WRITE_SIZE. R4: fixed (passA out of top-5).
__global__ void __launch_bounds__(1024, 8) passA(const int* __restrict__ src,
                                                 const int* __restrict__ dst,
                                                 int* __restrict__ gcnt,
                                                 int* __restrict__ storeA) {
    __shared__ int hist[1024];    // per-bucket count (977 used)
    __shared__ int lbase[1024];   // local exclusive scan (bucket start in stage)
    __shared__ int lcur[1024];    // local scatter cursor
    __shared__ int gbase[1024];   // absolute base in storeA
    __shared__ int stage[TILE_A]; // 64 KB sorted tile
    const int tid = threadIdx.x;
    const int base = blockIdx.x * TILE_A;
    const int nt = min(TILE_A, NE - base);
    hist[tid] = 0;
    __syncthreads();
    for (int i = tid; i < nt; i += 1024)
        atomicAdd(&hist[dst[base + i] >> 9], 1);
    __syncthreads();
    const int cnt = hist[tid];
    lbase[tid] = cnt;
    __syncthreads();
    // inclusive Hillis-Steele scan over 1024 bins
    for (int off = 1; off < 1024; off <<= 1) {
        int add = (tid >= off) ? lbase[tid - off] : 0;
        __syncthreads();
        lbase[tid] += add;
        __syncthreads();
    }
    const int lb = lbase[tid] - cnt;   // exclusive
    lcur[tid] = lb;
    if (tid < NBUCK && cnt > 0) {
        int g = atomicAdd(&gcnt[tid], cnt);
        gbase[tid] = tid * CAPA + g;
    }
    __syncthreads();
    lbase[tid] = lb;                   // publish exclusive base for write-out
    // scatter tile into LDS in bucket-sorted order
    for (int i = tid; i < nt; i += 1024) {
        int d = dst[base + i];
        int s = src[base + i];         // tile window L2-hot on re-read
        int p = atomicAdd(&lcur[d >> 9], 1);
        stage[p] = (s << 9) | (d & 511);
    }
    __syncthreads();
    // coalesced write-out: one bucket per wave iteration
    const int wid = tid >> 6, lane = tid & 63;
    for (int b = wid; b < NBUCK; b += 16) {
        int c = hist[b];
        if (c == 0) continue;
        int l0 = lbase[b];
        int g0 = gbase[b];
        int wl = min(c, (b + 1) * CAPA - g0);  // statistically never clips
        for (int j = lane; j < wl; j += 64)
            storeA[g0 + j] = stage[l0 + j];
    }
}

// ---------------- pass B: per-bucket sort by (SLICE, dst) ----------------
// R4: LDS-staged write-out fixed the 10.8x write amplification (out of top-5).
// R5 re-key: was (pair,dst,parity) -> 4 phases x 2 MB gather slice; FETCH 362 MB
// showed ~28% of gathers missing L2 (block phase-drift -> 4-6 MB live > 4 MB L2).
// Now key = (slice,dst): 8 phases x 1 MB slice; +-1 phase drift stays <= 3 MB.
// key(e): slice = e>>25 (3b), dst = e&511 -> key = (slice<<9)|dst, 4096 bins.
__global__ void __launch_bounds__(512) passB(const int* __restrict__ gcnt,
                                             const int* __restrict__ storeA,
                                             int* __restrict__ sortedB,
                                             float* __restrict__ inv,
                                             int* __restrict__ soff) {
    __shared__ int hist[NKEY];    // 16 KB: counts, then (after scan) scatter cursors
    __shared__ int sc[512];       // 2 KB
    __shared__ int stage[CAPA];   // 68 KB sorted bucket
    const int bkt = blockIdx.x;
    const int tid = threadIdx.x;
#pragma unroll
    for (int u = 0; u < NKEY / 512; ++u) hist[tid + u * 512] = 0;
    __syncthreads();
    const int n = min(gcnt[bkt], CAPA);
    const int* bs = storeA + (size_t)bkt * CAPA;
    // histogram (dwordx4 reads; bs is 16B-aligned, tail scalar)
    const int n4 = n & ~3;
    for (int k = tid * 4; k < n4; k += 2048) {
        int4v e4 = *(const int4v*)(bs + k);
#pragma unroll
        for (int u = 0; u < 4; ++u) {
            int e = e4[u];
            int key = ((e >> 25) << 9) | (e & 511);
            atomicAdd(&hist[key], 1);
        }
    }
    for (int k = n4 + tid; k < n; k += 512) {
        int e = bs[k];
        int key = ((e >> 25) << 9) | (e & 511);
        atomicAdd(&hist[key], 1);
    }
    __syncthreads();
    // inv[] from per-dst counts (sum over 8 slices)
    {
        int node = bkt * BN + tid;
        if (node < NN) {
            int c = 0;
#pragma unroll
            for (int s = 0; s < NSLICE; ++s)
                c += hist[(s << 9) | tid];
            inv[node] = 1.0f / fmaxf((float)c, 1.0f);
        }
    }
    // exclusive scan of 4096 bins: 8 bins per thread (hist dead after v[u] load)
    int v[NKEY / 512];
    int sum = 0;
#pragma unroll
    for (int u = 0; u < NKEY / 512; ++u) {
        v[u] = hist[tid * (NKEY / 512) + u];
        sum += v[u];
    }
    sc[tid] = sum;
    __syncthreads();
    for (int off = 1; off < 512; off <<= 1) {
        int add = (tid >= off) ? sc[tid - off] : 0;
        __syncthreads();
        sc[tid] += add;
        __syncthreads();
    }
    int run = sc[tid] - sum;           // LOCAL exclusive offset within bucket
    // slice start offsets (absolute): bin s<<9 is the first bin of thread s*64
    if ((tid & 63) == 0) soff[bkt * 9 + (tid >> 6)] = bkt * CAPA + run;
    if (tid == 511) soff[bkt * 9 + 8] = bkt * CAPA + n;
    // overwrite own hist bins with local scatter cursors
#pragma unroll
    for (int u = 0; u < NKEY / 512; ++u) {
        hist[tid * (NKEY / 512) + u] = run;
        run += v[u];
    }
    __syncthreads();
    // scatter into LDS stage (local positions)
    for (int k = tid * 4; k < n4; k += 2048) {
        int4v e4 = *(const int4v*)(bs + k);
#pragma unroll
        for (int u = 0; u < 4; ++u) {
            int e = e4[u];
            int key = ((e >> 25) << 9) | (e & 511);
            int p = atomicAdd(&hist[key], 1);
            stage[p] = e;
        }
    }
    for (int k = n4 + tid; k < n; k += 512) {
        int e = bs[k];
        int key = ((e >> 25) << 9) | (e & 511);
        int p = atomicAdd(&hist[key], 1);
        stage[p] = e;
    }
    __syncthreads();
    // contiguous, vectorized write-out: full lines, temporally clustered
    int* ob = sortedB + (size_t)bkt * CAPA;
    for (int k = tid * 4; k < n4; k += 2048)
        *(int4v*)(ob + k) = *(const int4v*)(stage + k);
    for (int k = n4 + tid; k < n; k += 512)
        ob[k] = stage[k];
}

// ---------------- layer-1 pre-transform: x @ Wl1.T (10 -> 5), bf16x5 packed in 16 B ----------------
__global__ void __launch_bounds__(256) transform0(const float* __restrict__ x,
                                                  const float* __restrict__ Wl1,
                                                  uint4* __restrict__ t16) {
    int i = blockIdx.x * 256 + threadIdx.x;
    if (i >= NN) return;
    float xi[10];
#pragma unroll
    for (int k = 0; k < 10; ++k) xi[k] = x[i * 10 + k];
    float v[5];
#pragma unroll
    for (int j = 0; j < 5; ++j) {
        float a = 0.f;
#pragma unroll
        for (int k = 0; k < 10; ++k) a += xi[k] * Wl1[j * 10 + k];
        v[j] = a;
    }
    uint4 w;
    w.x = bfr(v[0]) | (bfr(v[1]) << 16);
    w.y = bfr(v[2]) | (bfr(v[3]) << 16);
    w.z = bfr(v[4]);
    w.w = 0;
    t16[i] = w;
}

// ---------------- core: process sorted edge range, register acc, flush on dst change ----------------
__device__ __forceinline__ void process_range5(const int* __restrict__ sorted,
                                               int k, const int ke,
                                               const uint4* __restrict__ t16,
                                               float* __restrict__ acc) {
    int cur = -1;
    float a0 = 0, a1 = 0, a2 = 0, a3 = 0, a4 = 0;
    auto flush = [&]() {
        if (cur >= 0) {
            float* p = &acc[cur * 5];
            atomicAdd(p + 0, a0); atomicAdd(p + 1, a1); atomicAdd(p + 2, a2);
            atomicAdd(p + 3, a3); atomicAdd(p + 4, a4);
        }
    };
    auto edge = [&](int e, uint4 w) {
        int d = e & 511;
        if (d != cur) { flush(); cur = d; a0 = a1 = a2 = a3 = a4 = 0.f; }
        a0 += bfl(w.x); a1 += bfh(w.x); a2 += bfl(w.y); a3 += bfh(w.y); a4 += bfl(w.z);
    };
    // scalar prologue: align k to 16 B
    while (k < ke && (k & 3)) {
        int e = sorted[k];
        edge(e, t16[e >> 9]);
        ++k;
    }
    for (; k + 3 < ke; k += 4) {
        int4v e4 = __builtin_nontemporal_load((const int4v*)(sorted + k));
        uint4 w0 = t16[e4.x >> 9];
        uint4 w1 = t16[e4.y >> 9];
        uint4 w2 = t16[e4.z >> 9];
        uint4 w3 = t16[e4.w >> 9];
        edge(e4.x, w0); edge(e4.y, w1); edge(e4.z, w2); edge(e4.w, w3);
    }
    for (; k < ke; ++k) {
        int e = sorted[k];
        edge(e, t16[e >> 9]);
    }
    flush();
}

// ---------------- fused layer: per-SLICE phased sweep (LDS acc), node update + next pre-transform ----
// R1 lesson: full-range sweep -> 8 MB gather set -> L3. R5 counters: 2 MB pair
// slices still leaked (FETCH 362 MB, ~28% gather L2-miss from phase drift).
// Now 8 phases x 1 MB slice with a block barrier each: drift-tolerant (<=3 MB).
template <int FIN, int FNEXT>
__global__ void __launch_bounds__(512) layer_fused(const int* __restrict__ soff,
                                                   const int* __restrict__ sorted,
                                                   const uint4* __restrict__ t16,
                                                   const float* __restrict__ hin,
                                                   const float* __restrict__ Wr,
                                                   const float* __restrict__ b,
                                                   const float* __restrict__ Wln,
                                                   const float* __restrict__ inv,
                                                   float* __restrict__ hout,
                                                   uint4* __restrict__ tn16,
                                                   float* __restrict__ tnP) {
    __shared__ float acc[BN * 5];
    const int bkt = blockIdx.x;
    const int tid = threadIdx.x;
    for (int k = tid; k < BN * 5; k += 512) acc[k] = 0.f;
    __syncthreads();
#pragma unroll
    for (int p = 0; p < NSLICE; ++p) {
        int beg = soff[bkt * 9 + p], end = soff[bkt * 9 + p + 1];
        int c = (end - beg + 511) >> 9;
        int k = beg + tid * c;
        int ke = min(k + c, end);
        if (k < ke) process_range5(sorted, k, ke, t16, acc);
        __syncthreads();
    }

    int node = bkt * BN + tid;
    if (node >= NN) return;
    float iv = inv[node];
    float vin[FIN];
#pragma unroll
    for (int kk = 0; kk < FIN; ++kk) vin[kk] = hin[(size_t)node * FIN + kk];
    float ho[5];
#pragma unroll
    for (int jo = 0; jo < 5; ++jo) {
        float v = acc[tid * 5 + jo] * iv + b[jo];
#pragma unroll
        for (int kk = 0; kk < FIN; ++kk) v += vin[kk] * Wr[jo * FIN + kk];
        v = fmaxf(v, 0.f);
        hout[(size_t)node * 5 + jo] = v;
        ho[jo] = v;
    }
    if constexpr (FNEXT == 5) {
        float tv[5];
#pragma unroll
        for (int j2 = 0; j2 < 5; ++j2) {
            float v = 0.f;
#pragma unroll
            for (int jo = 0; jo < 5; ++jo) v += ho[jo] * Wln[j2 * 5 + jo];
            tv[j2] = v;
        }
        uint4 w;
        w.x = bfr(tv[0]) | (bfr(tv[1]) << 16);
        w.y = bfr(tv[2]) | (bfr(tv[3]) << 16);
        w.z = bfr(tv[4]);
        w.w = 0;
        tn16[node] = w;
    } else {  // FNEXT == 1: fp32 stride-1 plane for the final layer
        float v = 0.f;
#pragma unroll
        for (int jo = 0; jo < 5; ++jo) v += ho[jo] * Wln[jo];
        tnP[node] = v;
    }
}

// ---------------- final layer (5 -> 1): full range, t is a 2 MB fp32 plane (L2-fits) ----
__global__ void __launch_bounds__(512) final_layer(const int* __restrict__ soff,
                                                   const int* __restrict__ sorted,
                                                   const float* __restrict__ t,
                                                   const float* __restrict__ hin,
                                                   const float* __restrict__ Wr,
                                                   const float* __restrict__ b,
                                                   const float* __restrict__ inv,
                                                   float* __restrict__ out) {
    __shared__ float acc[BN];
    const int bkt = blockIdx.x;
    const int tid = threadIdx.x;
    if (tid < BN) acc[tid] = 0.f;  // BN==512
    __syncthreads();
    int beg = soff[bkt * 9], end = soff[bkt * 9 + 8];
    int c = (end - beg + 511) >> 9;
    int k = beg + tid * c;
    const int ke = min(k + c, end);
    int cur = -1;
    float a0 = 0.f;
    auto flush = [&]() { if (cur >= 0) atomicAdd(&acc[cur], a0); };
    auto edge = [&](int e, float q) {
        int d = e & 511;
        if (d != cur) { flush(); cur = d; a0 = 0.f; }
        a0 += q;
    };
    int kk = k;
    while (kk < ke && (kk & 3)) { int e = sorted[kk]; edge(e, t[e >> 9]); ++kk; }
    for (; kk + 3 < ke; kk += 4) {
        int4v e4 = __builtin_nontemporal_load((const int4v*)(sorted + kk));
        float q0 = t[e4.x >> 9], q1 = t[e4.y >> 9], q2 = t[e4.z >> 9], q3 = t[e4.w >> 9];
        edge(e4.x, q0); edge(e4.y, q1); edge(e4.z, q2); edge(e4.w, q3);
    }
    for (; kk < ke; ++kk) { int e = sorted[kk]; edge(e, t[e >> 9]); }
    flush();
    __syncthreads();
    int node = bkt * BN + tid;
    if (node >= NN) return;
    float v = acc[tid] * inv[node] + b[0];
#pragma unroll
    for (int kq = 0; kq < 5; ++kq) v += hin[(size_t)node * 5 + kq] * Wr[kq];
    out[node] = v;
}

extern "C" void kernel_launch(void* const* d_in, const int* in_sizes, int n_in,
                              void* d_out, int out_size, void* d_ws, size_t ws_size,
                              hipStream_t stream) {
    (void)in_sizes; (void)n_in; (void)out_size; (void)ws_size;
    const float* x    = (const float*)d_in[0];
    const int*   ei   = (const int*)d_in[1];
    const float* Wl1  = (const float*)d_in[2];
    const float* Wr1  = (const float*)d_in[3];
    const float* b1   = (const float*)d_in[4];
    const float* Wlm  = (const float*)d_in[5];
    const float* Wrm  = (const float*)d_in[6];
    const float* bm   = (const float*)d_in[7];
    const float* Wl10 = (const float*)d_in[8];
    const float* Wr10 = (const float*)d_in[9];
    const float* b10  = (const float*)d_in[10];
    float* out = (float*)d_out;

    const int* src = ei;
    const int* dst = ei + NE;

    // workspace layout (4-byte units)
    int* wsI = (int*)d_ws;
    int*   gcnt    = wsI;                         // 977 -> pad 1024
    int*   soff    = wsI + 1024;                  // 977*9 used at stride 9 (9 live)
    int*   sortedB = wsI + 10240;                 // 977*17408 = 17,007,616
    float* inv     = (float*)(wsI + 17017856);    // 500,224
    int*   storeA  = wsI + 20019200;              // 17,007,616 (dead after passB)
    // feature tables alias the dead storeA region (9.5M ints < 17M):
    uint4* tA = (uint4*)(wsI + 20019200);         // NN uint4 = 2,000,000 ints (16B-aligned)
    uint4* tB = (uint4*)(wsI + 22019200);         // 2,000,000 ints
    float* tP = (float*)(wsI + 24019200);         // 500,224 (final-layer fp32 plane)
    float* hA = (float*)(wsI + 24519424);         // 2,500,608
    float* hB = (float*)(wsI + 27020032);         // 2,500,608 -> end 29,520,640

    dim3 gb(NBUCK);
    dim3 tb(512);

    // ---- build: two-pass (dst-bucket, then (slice,dst) sort) ----
    hipMemsetAsync(gcnt, 0, 1024 * sizeof(int), stream);
    passA<<<dim3(NTILE_A), dim3(1024), 0, stream>>>(src, dst, gcnt, storeA);
    passB<<<gb, tb, 0, stream>>>(gcnt, storeA, sortedB, inv, soff);

    // ---- layer 1 (10 -> 5) ----  (transform0 overwrites storeA AFTER passB)
    transform0<<<dim3(NB_NODE), dim3(256), 0, stream>>>(x, Wl1, tA);
    layer_fused<10, 5><<<gb, tb, 0, stream>>>(soff, sortedB, tA,
                                              x, Wr1, b1, Wlm, inv, hA, tB, nullptr);

    // ---- middle layers 0..6 (5 -> 5) ----
    const uint4* tcur = tB; uint4* tnxt = tA;
    const float* hcur = hA; float* hnext = hB;
    for (int mi = 0; mi < 7; ++mi) {
        layer_fused<5, 5><<<gb, tb, 0, stream>>>(soff, sortedB, tcur,
                                                 hcur, Wrm + mi * 25, bm + mi * 5,
                                                 Wlm + (mi + 1) * 25, inv, hnext,
                                                 tnxt, nullptr);
        const uint4* tt = tcur; tcur = tnxt; tnxt = (uint4*)tt;
        const float* th = hcur; hcur = hnext; hnext = (float*)th;
    }
    // ---- middle layer 7: next pre-transform is final (5 -> 1) -> fp32 plane ----
    layer_fused<5, 1><<<gb, tb, 0, stream>>>(soff, sortedB, tcur,
                                             hcur, Wrm + 7 * 25, bm + 7 * 5,
                                             Wl10, inv, hnext, nullptr, tP);
    // ---- final layer (5 -> 1), no relu ----
    final_layer<<<gb, tb, 0, stream>>>(soff, sortedB, tP, hnext, Wr10, b10, inv, out);
}

// Round 9
// 1917.245 us; speedup vs baseline: 1.1114x; 1.1114x over previous
//
#include <hip/hip_runtime.h>

constexpr int NN = 500000;
constexpr int NE = 16000000;
constexpr int BN = 512;                       // dst nodes per bucket
constexpr int NBUCK = (NN + BN - 1) / BN;     // 977
constexpr int NSLICE = 8;                     // src slices of 65536 nodes
constexpr int NKEY = NSLICE * BN;             // 4096 sort bins per bucket
constexpr int CAPA = 17408;                   // per-bucket cap: mean 16384, +8 sigma
constexpr int TILE_A = 16384;                 // edges per pass-A tile (LDS-staged)
constexpr int NTILE_A = (NE + TILE_A - 1) / TILE_A; // 977
constexpr int NB_NODE = (NN + 255) / 256;     // 1954

typedef int int4v __attribute__((ext_vector_type(4)));

// ---------------- bf16 helpers ----------------
__device__ __forceinline__ unsigned bfr(float x) {   // fp32 -> bf16 bits (RNE)
    unsigned u = __float_as_uint(x);
    u += 0x7fffu + ((u >> 16) & 1u);
    return u >> 16;
}
__device__ __forceinline__ float bfl(unsigned u) { return __uint_as_float(u << 16); }
__device__ __forceinline__ float bfh(unsigned u) { return __uint_as_float(u & 0xffff0000u); }

// ---------------- pass A: LDS counting sort per tile, coalesced bucket write-out ----
// R1: scattered 4B stores -> 392 MB WRITE_SIZE. R4: fixed (passA out of top-5).
__global__ void __launch_bounds__(1024, 8) passA(const int* __restrict__ src,
                                                 const int* __restrict__ dst,
                                                 int* __restrict__ gcnt,
                                                 int* __restrict__ storeA) {
    __shared__ int hist[1024];    // per-bucket count (977 used)
    __shared__ int lbase[1024];   // local exclusive scan (bucket start in stage)
    __shared__ int lcur[1024];    // local scatter cursor
    __shared__ int gbase[1024];   // absolute base in storeA
    __shared__ int stage[TILE_A]; // 64 KB sorted tile
    const int tid = threadIdx.x;
    const int base = blockIdx.x * TILE_A;
    const int nt = min(TILE_A, NE - base);
    hist[tid] = 0;
    __syncthreads();
    for (int i = tid; i < nt; i += 1024)
        atomicAdd(&hist[dst[base + i] >> 9], 1);
    __syncthreads();
    const int cnt = hist[tid];
    lbase[tid] = cnt;
    __syncthreads();
    // inclusive Hillis-Steele scan over 1024 bins
    for (int off = 1; off < 1024; off <<= 1) {
        int add = (tid >= off) ? lbase[tid - off] : 0;
        __syncthreads();
        lbase[tid] += add;
        __syncthreads();
    }
    const int lb = lbase[tid] - cnt;   // exclusive
    lcur[tid] = lb;
    if (tid < NBUCK && cnt > 0) {
        int g = atomicAdd(&gcnt[tid], cnt);
        gbase[tid] = tid * CAPA + g;
    }
    __syncthreads();
    lbase[tid] = lb;                   // publish exclusive base for write-out
    // scatter tile into LDS in bucket-sorted order
    for (int i = tid; i < nt; i += 1024) {
        int d = dst[base + i];
        int s = src[base + i];         // tile window L2-hot on re-read
        int p = atomicAdd(&lcur[d >> 9], 1);
        stage[p] = (s << 9) | (d & 511);
    }
    __syncthreads();
    // coalesced write-out: one bucket per wave iteration
    const int wid = tid >> 6, lane = tid & 63;
    for (int b = wid; b < NBUCK; b += 16) {
        int c = hist[b];
        if (c == 0) continue;
        int l0 = lbase[b];
        int g0 = gbase[b];
        int wl = min(c, (b + 1) * CAPA - g0);  // statistically never clips
        for (int j = lane; j < wl; j += 64)
            storeA[g0 + j] = stage[l0 + j];
    }
}

// ---------------- pass B: per-bucket sort by (SLICE, dst) ----------------
// R4: LDS-staged write-out fixed the 10.8x write amplification.
// key(e): slice = e>>25 (3b), dst = e&511 -> key = (slice<<9)|dst, 4096 bins.
// soff keeps all 8 slice starts; the consumer chooses its phase granularity.
__global__ void __launch_bounds__(512) passB(const int* __restrict__ gcnt,
                                             const int* __restrict__ storeA,
                                             int* __restrict__ sortedB,
                                             float* __restrict__ inv,
                                             int* __restrict__ soff) {
    __shared__ int hist[NKEY];    // 16 KB: counts, then (after scan) scatter cursors
    __shared__ int sc[512];       // 2 KB
    __shared__ int stage[CAPA];   // 68 KB sorted bucket
    const int bkt = blockIdx.x;
    const int tid = threadIdx.x;
#pragma unroll
    for (int u = 0; u < NKEY / 512; ++u) hist[tid + u * 512] = 0;
    __syncthreads();
    const int n = min(gcnt[bkt], CAPA);
    const int* bs = storeA + (size_t)bkt * CAPA;
    // histogram (dwordx4 reads; bs is 16B-aligned, tail scalar)
    const int n4 = n & ~3;
    for (int k = tid * 4; k < n4; k += 2048) {
        int4v e4 = *(const int4v*)(bs + k);
#pragma unroll
        for (int u = 0; u < 4; ++u) {
            int e = e4[u];
            int key = ((e >> 25) << 9) | (e & 511);
            atomicAdd(&hist[key], 1);
        }
    }
    for (int k = n4 + tid; k < n; k += 512) {
        int e = bs[k];
        int key = ((e >> 25) << 9) | (e & 511);
        atomicAdd(&hist[key], 1);
    }
    __syncthreads();
    // inv[] from per-dst counts (sum over 8 slices)
    {
        int node = bkt * BN + tid;
        if (node < NN) {
            int c = 0;
#pragma unroll
            for (int s = 0; s < NSLICE; ++s)
                c += hist[(s << 9) | tid];
            inv[node] = 1.0f / fmaxf((float)c, 1.0f);
        }
    }
    // exclusive scan of 4096 bins: 8 bins per thread (hist dead after v[u] load)
    int v[NKEY / 512];
    int sum = 0;
#pragma unroll
    for (int u = 0; u < NKEY / 512; ++u) {
        v[u] = hist[tid * (NKEY / 512) + u];
        sum += v[u];
    }
    sc[tid] = sum;
    __syncthreads();
    for (int off = 1; off < 512; off <<= 1) {
        int add = (tid >= off) ? sc[tid - off] : 0;
        __syncthreads();
        sc[tid] += add;
        __syncthreads();
    }
    int run = sc[tid] - sum;           // LOCAL exclusive offset within bucket
    // slice start offsets (absolute): bin s<<9 is the first bin of thread s*64
    if ((tid & 63) == 0) soff[bkt * 9 + (tid >> 6)] = bkt * CAPA + run;
    if (tid == 511) soff[bkt * 9 + 8] = bkt * CAPA + n;
    // overwrite own hist bins with local scatter cursors
#pragma unroll
    for (int u = 0; u < NKEY / 512; ++u) {
        hist[tid * (NKEY / 512) + u] = run;
        run += v[u];
    }
    __syncthreads();
    // scatter into LDS stage (local positions)
    for (int k = tid * 4; k < n4; k += 2048) {
        int4v e4 = *(const int4v*)(bs + k);
#pragma unroll
        for (int u = 0; u < 4; ++u) {
            int e = e4[u];
            int key = ((e >> 25) << 9) | (e & 511);
            int p = atomicAdd(&hist[key], 1);
            stage[p] = e;
        }
    }
    for (int k = n4 + tid; k < n; k += 512) {
        int e = bs[k];
        int key = ((e >> 25) << 9) | (e & 511);
        int p = atomicAdd(&hist[key], 1);
        stage[p] = e;
    }
    __syncthreads();
    // contiguous, vectorized write-out: full lines, temporally clustered
    int* ob = sortedB + (size_t)bkt * CAPA;
    for (int k = tid * 4; k < n4; k += 2048)
        *(int4v*)(ob + k) = *(const int4v*)(stage + k);
    for (int k = n4 + tid; k < n; k += 512)
        ob[k] = stage[k];
}

// ---------------- layer-1 pre-transform: x @ Wl1.T (10 -> 5), bf16x5 packed in 16 B ----------------
__global__ void __launch_bounds__(256) transform0(const float* __restrict__ x,
                                                  const float* __restrict__ Wl1,
                                                  uint4* __restrict__ t16) {
    int i = blockIdx.x * 256 + threadIdx.x;
    if (i >= NN) return;
    float xi[10];
#pragma unroll
    for (int k = 0; k < 10; ++k) xi[k] = x[i * 10 + k];
    float v[5];
#pragma unroll
    for (int j = 0; j < 5; ++j) {
        float a = 0.f;
#pragma unroll
        for (int k = 0; k < 10; ++k) a += xi[k] * Wl1[j * 10 + k];
        v[j] = a;
    }
    uint4 w;
    w.x = bfr(v[0]) | (bfr(v[1]) << 16);
    w.y = bfr(v[2]) | (bfr(v[3]) << 16);
    w.z = bfr(v[4]);
    w.w = 0;
    t16[i] = w;
}

// ---------------- core: process sorted edge range, register acc, flush on dst change ----------------
// R8 lesson: the sweep is gather-latency x MLP bound (16M gathers / 20 waves/CU
// / 4-in-flight * ~430cy ~ 150us). 8-wide iteration doubles in-flight gathers:
// 2x dwordx4 edge loads issue back-to-back, then 8 independent t16 gathers are
// outstanding before the first consume.
__device__ __forceinline__ void process_range5(const int* __restrict__ sorted,
                                               int k, const int ke,
                                               const uint4* __restrict__ t16,
                                               float* __restrict__ acc) {
    int cur = -1;
    float a0 = 0, a1 = 0, a2 = 0, a3 = 0, a4 = 0;
    auto flush = [&]() {
        if (cur >= 0) {
            float* p = &acc[cur * 5];
            atomicAdd(p + 0, a0); atomicAdd(p + 1, a1); atomicAdd(p + 2, a2);
            atomicAdd(p + 3, a3); atomicAdd(p + 4, a4);
        }
    };
    auto edge = [&](int e, uint4 w) {
        int d = e & 511;
        if (d != cur) { flush(); cur = d; a0 = a1 = a2 = a3 = a4 = 0.f; }
        a0 += bfl(w.x); a1 += bfh(w.x); a2 += bfl(w.y); a3 += bfh(w.y); a4 += bfl(w.z);
    };
    // scalar prologue: align k to 16 B
    while (k < ke && (k & 3)) {
        int e = sorted[k];
        edge(e, t16[e >> 9]);
        ++k;
    }
    // 8-wide main loop: 8 gathers in flight
    for (; k + 7 < ke; k += 8) {
        int4v ea = __builtin_nontemporal_load((const int4v*)(sorted + k));
        int4v eb = __builtin_nontemporal_load((const int4v*)(sorted + k + 4));
        uint4 w0 = t16[ea.x >> 9];
        uint4 w1 = t16[ea.y >> 9];
        uint4 w2 = t16[ea.z >> 9];
        uint4 w3 = t16[ea.w >> 9];
        uint4 w4 = t16[eb.x >> 9];
        uint4 w5 = t16[eb.y >> 9];
        uint4 w6 = t16[eb.z >> 9];
        uint4 w7 = t16[eb.w >> 9];
        edge(ea.x, w0); edge(ea.y, w1); edge(ea.z, w2); edge(ea.w, w3);
        edge(eb.x, w4); edge(eb.y, w5); edge(eb.z, w6); edge(eb.w, w7);
    }
    // 4-wide cleanup
    for (; k + 3 < ke; k += 4) {
        int4v e4 = __builtin_nontemporal_load((const int4v*)(sorted + k));
        uint4 w0 = t16[e4.x >> 9];
        uint4 w1 = t16[e4.y >> 9];
        uint4 w2 = t16[e4.z >> 9];
        uint4 w3 = t16[e4.w >> 9];
        edge(e4.x, w0); edge(e4.y, w1); edge(e4.z, w2); edge(e4.w, w3);
    }
    for (; k < ke; ++k) {
        int e = sorted[k];
        edge(e, t16[e >> 9]);
    }
    flush();
}

// ---------------- fused layer: 4 phases x 2 slices (LDS acc), node update + next pre-transform ----
// R5: 4x2MB phases, c~8 -> 154us. R8: 8x1MB phases, c~4 -> 196us DESPITE FETCH
// 362->197MB: latency-MLP-bound, not locality-bound. Now: back to 4 phases
// (c~8 supports the 8-wide iteration) on the 8-slice sort; barriers are pacing
// only (acc is additive per-block LDS -> no cross-phase dependence).
template <int FIN, int FNEXT>
__global__ void __launch_bounds__(512) layer_fused(const int* __restrict__ soff,
                                                   const int* __restrict__ sorted,
                                                   const uint4* __restrict__ t16,
                                                   const float* __restrict__ hin,
                                                   const float* __restrict__ Wr,
                                                   const float* __restrict__ b,
                                                   const float* __restrict__ Wln,
                                                   const float* __restrict__ inv,
                                                   float* __restrict__ hout,
                                                   uint4* __restrict__ tn16,
                                                   float* __restrict__ tnP) {
    __shared__ float acc[BN * 5];
    const int bkt = blockIdx.x;
    const int tid = threadIdx.x;
    for (int k = tid; k < BN * 5; k += 512) acc[k] = 0.f;
    __syncthreads();
#pragma unroll
    for (int p = 0; p < 4; ++p) {
        int beg = soff[bkt * 9 + 2 * p], end = soff[bkt * 9 + 2 * p + 2];
        int c = (end - beg + 511) >> 9;
        int k = beg + tid * c;
        int ke = min(k + c, end);
        if (k < ke) process_range5(sorted, k, ke, t16, acc);
        __syncthreads();
    }

    int node = bkt * BN + tid;
    if (node >= NN) return;
    float iv = inv[node];
    float vin[FIN];
#pragma unroll
    for (int kk = 0; kk < FIN; ++kk) vin[kk] = hin[(size_t)node * FIN + kk];
    float ho[5];
#pragma unroll
    for (int jo = 0; jo < 5; ++jo) {
        float v = acc[tid * 5 + jo] * iv + b[jo];
#pragma unroll
        for (int kk = 0; kk < FIN; ++kk) v += vin[kk] * Wr[jo * FIN + kk];
        v = fmaxf(v, 0.f);
        hout[(size_t)node * 5 + jo] = v;
        ho[jo] = v;
    }
    if constexpr (FNEXT == 5) {
        float tv[5];
#pragma unroll
        for (int j2 = 0; j2 < 5; ++j2) {
            float v = 0.f;
#pragma unroll
            for (int jo = 0; jo < 5; ++jo) v += ho[jo] * Wln[j2 * 5 + jo];
            tv[j2] = v;
        }
        uint4 w;
        w.x = bfr(tv[0]) | (bfr(tv[1]) << 16);
        w.y = bfr(tv[2]) | (bfr(tv[3]) << 16);
        w.z = bfr(tv[4]);
        w.w = 0;
        tn16[node] = w;
    } else {  // FNEXT == 1: fp32 stride-1 plane for the final layer
        float v = 0.f;
#pragma unroll
        for (int jo = 0; jo < 5; ++jo) v += ho[jo] * Wln[jo];
        tnP[node] = v;
    }
}

// ---------------- final layer (5 -> 1): full range, t is a 2 MB fp32 plane (L2-fits) ----
__global__ void __launch_bounds__(512) final_layer(const int* __restrict__ soff,
                                                   const int* __restrict__ sorted,
                                                   const float* __restrict__ t,
                                                   const float* __restrict__ hin,
                                                   const float* __restrict__ Wr,
                                                   const float* __restrict__ b,
                                                   const float* __restrict__ inv,
                                                   float* __restrict__ out) {
    __shared__ float acc[BN];
    const int bkt = blockIdx.x;
    const int tid = threadIdx.x;
    if (tid < BN) acc[tid] = 0.f;  // BN==512
    __syncthreads();
    int beg = soff[bkt * 9], end = soff[bkt * 9 + 8];
    int c = (end - beg + 511) >> 9;
    int k = beg + tid * c;
    const int ke = min(k + c, end);
    int cur = -1;
    float a0 = 0.f;
    auto flush = [&]() { if (cur >= 0) atomicAdd(&acc[cur], a0); };
    auto edge = [&](int e, float q) {
        int d = e & 511;
        if (d != cur) { flush(); cur = d; a0 = 0.f; }
        a0 += q;
    };
    int kk = k;
    while (kk < ke && (kk & 3)) { int e = sorted[kk]; edge(e, t[e >> 9]); ++kk; }
    for (; kk + 7 < ke; kk += 8) {
        int4v ea = __builtin_nontemporal_load((const int4v*)(sorted + kk));
        int4v eb = __builtin_nontemporal_load((const int4v*)(sorted + kk + 4));
        float q0 = t[ea.x >> 9], q1 = t[ea.y >> 9], q2 = t[ea.z >> 9], q3 = t[ea.w >> 9];
        float q4 = t[eb.x >> 9], q5 = t[eb.y >> 9], q6 = t[eb.z >> 9], q7 = t[eb.w >> 9];
        edge(ea.x, q0); edge(ea.y, q1); edge(ea.z, q2); edge(ea.w, q3);
        edge(eb.x, q4); edge(eb.y, q5); edge(eb.z, q6); edge(eb.w, q7);
    }
    for (; kk + 3 < ke; kk += 4) {
        int4v e4 = __builtin_nontemporal_load((const int4v*)(sorted + kk));
        float q0 = t[e4.x >> 9], q1 = t[e4.y >> 9], q2 = t[e4.z >> 9], q3 = t[e4.w >> 9];
        edge(e4.x, q0); edge(e4.y, q1); edge(e4.z, q2); edge(e4.w, q3);
    }
    for (; kk < ke; ++kk) { int e = sorted[kk]; edge(e, t[e >> 9]); }
    flush();
    __syncthreads();
    int node = bkt * BN + tid;
    if (node >= NN) return;
    float v = acc[tid] * inv[node] + b[0];
#pragma unroll
    for (int kq = 0; kq < 5; ++kq) v += hin[(size_t)node * 5 + kq] * Wr[kq];
    out[node] = v;
}

extern "C" void kernel_launch(void* const* d_in, const int* in_sizes, int n_in,
                              void* d_out, int out_size, void* d_ws, size_t ws_size,
                              hipStream_t stream) {
    (void)in_sizes; (void)n_in; (void)out_size; (void)ws_size;
    const float* x    = (const float*)d_in[0];
    const int*   ei   = (const int*)d_in[1];
    const float* Wl1  = (const float*)d_in[2];
    const float* Wr1  = (const float*)d_in[3];
    const float* b1   = (const float*)d_in[4];
    const float* Wlm  = (const float*)d_in[5];
    const float* Wrm  = (const float*)d_in[6];
    const float* bm   = (const float*)d_in[7];
    const float* Wl10 = (const float*)d_in[8];
    const float* Wr10 = (const float*)d_in[9];
    const float* b10  = (const float*)d_in[10];
    float* out = (float*)d_out;

    const int* src = ei;
    const int* dst = ei + NE;

    // workspace layout (4-byte units)
    int* wsI = (int*)d_ws;
    int*   gcnt    = wsI;                         // 977 -> pad 1024
    int*   soff    = wsI + 1024;                  // 977*9 used at stride 9 (9 live)
    int*   sortedB = wsI + 10240;                 // 977*17408 = 17,007,616
    float* inv     = (float*)(wsI + 17017856);    // 500,224
    int*   storeA  = wsI + 20019200;              // 17,007,616 (dead after passB)
    // feature tables alias the dead storeA region (9.5M ints < 17M):
    uint4* tA = (uint4*)(wsI + 20019200);         // NN uint4 = 2,000,000 ints (16B-aligned)
    uint4* tB = (uint4*)(wsI + 22019200);         // 2,000,000 ints
    float* tP = (float*)(wsI + 24019200);         // 500,224 (final-layer fp32 plane)
    float* hA = (float*)(wsI + 24519424);         // 2,500,608
    float* hB = (float*)(wsI + 27020032);         // 2,500,608 -> end 29,520,640

    dim3 gb(NBUCK);
    dim3 tb(512);

    // ---- build: two-pass (dst-bucket, then (slice,dst) sort) ----
    hipMemsetAsync(gcnt, 0, 1024 * sizeof(int), stream);
    passA<<<dim3(NTILE_A), dim3(1024), 0, stream>>>(src, dst, gcnt, storeA);
    passB<<<gb, tb, 0, stream>>>(gcnt, storeA, sortedB, inv, soff);

    // ---- layer 1 (10 -> 5) ----  (transform0 overwrites storeA AFTER passB)
    transform0<<<dim3(NB_NODE), dim3(256), 0, stream>>>(x, Wl1, tA);
    layer_fused<10, 5><<<gb, tb, 0, stream>>>(soff, sortedB, tA,
                                              x, Wr1, b1, Wlm, inv, hA, tB, nullptr);

    // ---- middle layers 0..6 (5 -> 5) ----
    const uint4* tcur = tB; uint4* tnxt = tA;
    const float* hcur = hA; float* hnext = hB;
    for (int mi = 0; mi < 7; ++mi) {
        layer_fused<5, 5><<<gb, tb, 0, stream>>>(soff, sortedB, tcur,
                                                 hcur, Wrm + mi * 25, bm + mi * 5,
                                                 Wlm + (mi + 1) * 25, inv, hnext,
                                                 tnxt, nullptr);
        const uint4* tt = tcur; tcur = tnxt; tnxt = (uint4*)tt;
        const float* th = hcur; hcur = hnext; hnext = (float*)th;
    }
    // ---- middle layer 7: next pre-transform is final (5 -> 1) -> fp32 plane ----
    layer_fused<5, 1><<<gb, tb, 0, stream>>>(soff, sortedB, tcur,
                                             hcur, Wrm + 7 * 25, bm + 7 * 5,
                                             Wl10, inv, hnext, nullptr, tP);
    // ---- final layer (5 -> 1), no relu ----
    final_layer<<<gb, tb, 0, stream>>>(soff, sortedB, tP, hnext, Wr10, b10, inv, out);
}

// Round 11
// 1762.081 us; speedup vs baseline: 1.2093x; 1.0881x over previous
//
#include <hip/hip_runtime.h>

constexpr int NN = 500000;
constexpr int NE = 16000000;
constexpr int BN = 512;                       // dst nodes per bucket
constexpr int NBUCK = (NN + BN - 1) / BN;     // 977
constexpr int NSLICE = 8;                     // src slices of 65536 nodes
constexpr int NKEY = NSLICE * BN;             // 4096 sort bins per bucket
constexpr int CAPA = 17408;                   // per-bucket cap: mean 16384, +8 sigma
constexpr int TILE_A = 16384;                 // edges per pass-A tile (LDS-staged)
constexpr int NTILE_A = (NE + TILE_A - 1) / TILE_A; // 977
constexpr int NB_NODE = (NN + 255) / 256;     // 1954

typedef int int4v __attribute__((ext_vector_type(4)));

// ---------------- bf16 helpers ----------------
__device__ __forceinline__ unsigned bfr(float x) {   // fp32 -> bf16 bits (RNE)
    unsigned u = __float_as_uint(x);
    u += 0x7fffu + ((u >> 16) & 1u);
    return u >> 16;
}
__device__ __forceinline__ float bfl(unsigned u) { return __uint_as_float(u << 16); }
__device__ __forceinline__ float bfh(unsigned u) { return __uint_as_float(u & 0xffff0000u); }

// ---------------- pass A: LDS counting sort per tile, coalesced bucket write-out ----
// R1: scattered 4B stores -> 392 MB WRITE_SIZE. R4: fixed (passA out of top-5).
__global__ void __launch_bounds__(1024, 8) passA(const int* __restrict__ src,
                                                 const int* __restrict__ dst,
                                                 int* __restrict__ gcnt,
                                                 int* __restrict__ storeA) {
    __shared__ int hist[1024];    // per-bucket count (977 used)
    __shared__ int lbase[1024];   // local exclusive scan (bucket start in stage)
    __shared__ int lcur[1024];    // local scatter cursor
    __shared__ int gbase[1024];   // absolute base in storeA
    __shared__ int stage[TILE_A]; // 64 KB sorted tile
    const int tid = threadIdx.x;
    const int base = blockIdx.x * TILE_A;
    const int nt = min(TILE_A, NE - base);
    hist[tid] = 0;
    __syncthreads();
    for (int i = tid; i < nt; i += 1024)
        atomicAdd(&hist[dst[base + i] >> 9], 1);
    __syncthreads();
    const int cnt = hist[tid];
    lbase[tid] = cnt;
    __syncthreads();
    // inclusive Hillis-Steele scan over 1024 bins
    for (int off = 1; off < 1024; off <<= 1) {
        int add = (tid >= off) ? lbase[tid - off] : 0;
        __syncthreads();
        lbase[tid] += add;
        __syncthreads();
    }
    const int lb = lbase[tid] - cnt;   // exclusive
    lcur[tid] = lb;
    if (tid < NBUCK && cnt > 0) {
        int g = atomicAdd(&gcnt[tid], cnt);
        gbase[tid] = tid * CAPA + g;
    }
    __syncthreads();
    lbase[tid] = lb;                   // publish exclusive base for write-out
    // scatter tile into LDS in bucket-sorted order
    for (int i = tid; i < nt; i += 1024) {
        int d = dst[base + i];
        int s = src[base + i];         // tile window L2-hot on re-read
        int p = atomicAdd(&lcur[d >> 9], 1);
        stage[p] = (s << 9) | (d & 511);
    }
    __syncthreads();
    // coalesced write-out: one bucket per wave iteration
    const int wid = tid >> 6, lane = tid & 63;
    for (int b = wid; b < NBUCK; b += 16) {
        int c = hist[b];
        if (c == 0) continue;
        int l0 = lbase[b];
        int g0 = gbase[b];
        int wl = min(c, (b + 1) * CAPA - g0);  // statistically never clips
        for (int j = lane; j < wl; j += 64)
            storeA[g0 + j] = stage[l0 + j];
    }
}

// ---------------- pass B: per-bucket sort by (PAIR, dst, slice-parity) ----------------
// R9 lesson: the (slice,dst) key halved run length (~8 -> ~4), doubling LDS
// flush sequences; layer time 154 -> 174/196 us across R8/R9 while FETCH did
// NOT correlate with time (latency-bound, not BW). Revert to the R5 key:
// pair = slice>>1; all edges of one (pair,dst) across both parities form ONE
// ~8-edge run. 4 phases x 2 MB in the consumer.
// key(e): pair = e>>26, parity = (e>>25)&1, dst = e&511.
__global__ void __launch_bounds__(512) passB(const int* __restrict__ gcnt,
                                             const int* __restrict__ storeA,
                                             int* __restrict__ sortedB,
                                             float* __restrict__ inv,
                                             int* __restrict__ soff) {
    __shared__ int hist[NKEY];    // 16 KB: counts, then (after scan) scatter cursors
    __shared__ int sc[512];       // 2 KB
    __shared__ int stage[CAPA];   // 68 KB sorted bucket
    const int bkt = blockIdx.x;
    const int tid = threadIdx.x;
#pragma unroll
    for (int u = 0; u < NKEY / 512; ++u) hist[tid + u * 512] = 0;
    __syncthreads();
    const int n = min(gcnt[bkt], CAPA);
    const int* bs = storeA + (size_t)bkt * CAPA;
    // histogram (dwordx4 reads; bs is 16B-aligned, tail scalar)
    const int n4 = n & ~3;
    for (int k = tid * 4; k < n4; k += 2048) {
        int4v e4 = *(const int4v*)(bs + k);
#pragma unroll
        for (int u = 0; u < 4; ++u) {
            int e = e4[u];
            int key = ((e >> 26) << 10) | ((e & 511) << 1) | ((e >> 25) & 1);
            atomicAdd(&hist[key], 1);
        }
    }
    for (int k = n4 + tid; k < n; k += 512) {
        int e = bs[k];
        int key = ((e >> 26) << 10) | ((e & 511) << 1) | ((e >> 25) & 1);
        atomicAdd(&hist[key], 1);
    }
    __syncthreads();
    // inv[] from per-dst counts (sum over 4 pairs x 2 parities)
    {
        int node = bkt * BN + tid;
        if (node < NN) {
            int c = 0;
#pragma unroll
            for (int p = 0; p < 4; ++p)
#pragma unroll
                for (int q = 0; q < 2; ++q)
                    c += hist[(p << 10) | (tid << 1) | q];
            inv[node] = 1.0f / fmaxf((float)c, 1.0f);
        }
    }
    // exclusive scan of 4096 bins: 8 bins per thread (hist dead after v[u] load)
    int v[NKEY / 512];
    int sum = 0;
#pragma unroll
    for (int u = 0; u < NKEY / 512; ++u) {
        v[u] = hist[tid * (NKEY / 512) + u];
        sum += v[u];
    }
    sc[tid] = sum;
    __syncthreads();
    for (int off = 1; off < 512; off <<= 1) {
        int add = (tid >= off) ? sc[tid - off] : 0;
        __syncthreads();
        sc[tid] += add;
        __syncthreads();
    }
    int run = sc[tid] - sum;           // LOCAL exclusive offset within bucket
    // pair start offsets (absolute): bin p<<10 is the first bin of thread p*128
    if ((tid & 127) == 0) soff[bkt * 9 + (tid >> 7)] = bkt * CAPA + run;
    if (tid == 511) soff[bkt * 9 + 4] = bkt * CAPA + n;
    // overwrite own hist bins with local scatter cursors
#pragma unroll
    for (int u = 0; u < NKEY / 512; ++u) {
        hist[tid * (NKEY / 512) + u] = run;
        run += v[u];
    }
    __syncthreads();
    // scatter into LDS stage (local positions)
    for (int k = tid * 4; k < n4; k += 2048) {
        int4v e4 = *(const int4v*)(bs + k);
#pragma unroll
        for (int u = 0; u < 4; ++u) {
            int e = e4[u];
            int key = ((e >> 26) << 10) | ((e & 511) << 1) | ((e >> 25) & 1);
            int p = atomicAdd(&hist[key], 1);
            stage[p] = e;
        }
    }
    for (int k = n4 + tid; k < n; k += 512) {
        int e = bs[k];
        int key = ((e >> 26) << 10) | ((e & 511) << 1) | ((e >> 25) & 1);
        int p = atomicAdd(&hist[key], 1);
        stage[p] = e;
    }
    __syncthreads();
    // contiguous, vectorized write-out: full lines, temporally clustered
    int* ob = sortedB + (size_t)bkt * CAPA;
    for (int k = tid * 4; k < n4; k += 2048)
        *(int4v*)(ob + k) = *(const int4v*)(stage + k);
    for (int k = n4 + tid; k < n; k += 512)
        ob[k] = stage[k];
}

// ---------------- layer-1 pre-transform: x @ Wl1.T (10 -> 5), bf16x5 packed in 16 B ----------------
__global__ void __launch_bounds__(256) transform0(const float* __restrict__ x,
                                                  const float* __restrict__ Wl1,
                                                  uint4* __restrict__ t16) {
    int i = blockIdx.x * 256 + threadIdx.x;
    if (i >= NN) return;
    float xi[10];
#pragma unroll
    for (int k = 0; k < 10; ++k) xi[k] = x[i * 10 + k];
    float v[5];
#pragma unroll
    for (int j = 0; j < 5; ++j) {
        float a = 0.f;
#pragma unroll
        for (int k = 0; k < 10; ++k) a += xi[k] * Wl1[j * 10 + k];
        v[j] = a;
    }
    uint4 w;
    w.x = bfr(v[0]) | (bfr(v[1]) << 16);
    w.y = bfr(v[2]) | (bfr(v[3]) << 16);
    w.z = bfr(v[4]);
    w.w = 0;
    t16[i] = w;
}

// ---------------- core: process sorted edge range, register acc, flush on dst change ----------------
// 8-wide iteration: 2x dwordx4 edge loads, then 8 independent t16 gathers in
// flight before the first consume (R9; kept — isolated vs run-length this round).
__device__ __forceinline__ void process_range5(const int* __restrict__ sorted,
                                               int k, const int ke,
                                               const uint4* __restrict__ t16,
                                               float* __restrict__ acc) {
    int cur = -1;
    float a0 = 0, a1 = 0, a2 = 0, a3 = 0, a4 = 0;
    auto flush = [&]() {
        if (cur >= 0) {
            float* p = &acc[cur * 5];
            atomicAdd(p + 0, a0); atomicAdd(p + 1, a1); atomicAdd(p + 2, a2);
            atomicAdd(p + 3, a3); atomicAdd(p + 4, a4);
        }
    };
    auto edge = [&](int e, uint4 w) {
        int d = e & 511;
        if (d != cur) { flush(); cur = d; a0 = a1 = a2 = a3 = a4 = 0.f; }
        a0 += bfl(w.x); a1 += bfh(w.x); a2 += bfl(w.y); a3 += bfh(w.y); a4 += bfl(w.z);
    };
    // scalar prologue: align k to 16 B
    while (k < ke && (k & 3)) {
        int e = sorted[k];
        edge(e, t16[e >> 9]);
        ++k;
    }
    // 8-wide main loop: 8 gathers in flight
    for (; k + 7 < ke; k += 8) {
        int4v ea = __builtin_nontemporal_load((const int4v*)(sorted + k));
        int4v eb = __builtin_nontemporal_load((const int4v*)(sorted + k + 4));
        uint4 w0 = t16[ea.x >> 9];
        uint4 w1 = t16[ea.y >> 9];
        uint4 w2 = t16[ea.z >> 9];
        uint4 w3 = t16[ea.w >> 9];
        uint4 w4 = t16[eb.x >> 9];
        uint4 w5 = t16[eb.y >> 9];
        uint4 w6 = t16[eb.z >> 9];
        uint4 w7 = t16[eb.w >> 9];
        edge(ea.x, w0); edge(ea.y, w1); edge(ea.z, w2); edge(ea.w, w3);
        edge(eb.x, w4); edge(eb.y, w5); edge(eb.z, w6); edge(eb.w, w7);
    }
    // 4-wide cleanup
    for (; k + 3 < ke; k += 4) {
        int4v e4 = __builtin_nontemporal_load((const int4v*)(sorted + k));
        uint4 w0 = t16[e4.x >> 9];
        uint4 w1 = t16[e4.y >> 9];
        uint4 w2 = t16[e4.z >> 9];
        uint4 w3 = t16[e4.w >> 9];
        edge(e4.x, w0); edge(e4.y, w1); edge(e4.z, w2); edge(e4.w, w3);
    }
    for (; k < ke; ++k) {
        int e = sorted[k];
        edge(e, t16[e >> 9]);
    }
    flush();
}

// ---------------- fused layer: 4 pair-phases (LDS acc), node update + next pre-transform ----
// R5 structure: 4 phases x 2 MB gather slice (pair sort, ~8-edge runs), c~8/thread.
template <int FIN, int FNEXT>
__global__ void __launch_bounds__(512) layer_fused(const int* __restrict__ soff,
                                                   const int* __restrict__ sorted,
                                                   const uint4* __restrict__ t16,
                                                   const float* __restrict__ hin,
                                                   const float* __restrict__ Wr,
                                                   const float* __restrict__ b,
                                                   const float* __restrict__ Wln,
                                                   const float* __restrict__ inv,
                                                   float* __restrict__ hout,
                                                   uint4* __restrict__ tn16,
                                                   float* __restrict__ tnP) {
    __shared__ float acc[BN * 5];
    const int bkt = blockIdx.x;
    const int tid = threadIdx.x;
    for (int k = tid; k < BN * 5; k += 512) acc[k] = 0.f;
    __syncthreads();
#pragma unroll
    for (int p = 0; p < 4; ++p) {
        int beg = soff[bkt * 9 + p], end = soff[bkt * 9 + p + 1];
        int c = (end - beg + 511) >> 9;
        int k = beg + tid * c;
        int ke = min(k + c, end);
        if (k < ke) process_range5(sorted, k, ke, t16, acc);
        __syncthreads();
    }

    int node = bkt * BN + tid;
    if (node >= NN) return;
    float iv = inv[node];
    float vin[FIN];
#pragma unroll
    for (int kk = 0; kk < FIN; ++kk) vin[kk] = hin[(size_t)node * FIN + kk];
    float ho[5];
#pragma unroll
    for (int jo = 0; jo < 5; ++jo) {
        float v = acc[tid * 5 + jo] * iv + b[jo];
#pragma unroll
        for (int kk = 0; kk < FIN; ++kk) v += vin[kk] * Wr[jo * FIN + kk];
        v = fmaxf(v, 0.f);
        hout[(size_t)node * 5 + jo] = v;
        ho[jo] = v;
    }
    if constexpr (FNEXT == 5) {
        float tv[5];
#pragma unroll
        for (int j2 = 0; j2 < 5; ++j2) {
            float v = 0.f;
#pragma unroll
            for (int jo = 0; jo < 5; ++jo) v += ho[jo] * Wln[j2 * 5 + jo];
            tv[j2] = v;
        }
        uint4 w;
        w.x = bfr(tv[0]) | (bfr(tv[1]) << 16);
        w.y = bfr(tv[2]) | (bfr(tv[3]) << 16);
        w.z = bfr(tv[4]);
        w.w = 0;
        tn16[node] = w;
    } else {  // FNEXT == 1: fp32 stride-1 plane for the final layer
        float v = 0.f;
#pragma unroll
        for (int jo = 0; jo < 5; ++jo) v += ho[jo] * Wln[jo];
        tnP[node] = v;
    }
}

// ---------------- final layer (5 -> 1): full range, t is a 2 MB fp32 plane (L2-fits) ----
__global__ void __launch_bounds__(512) final_layer(const int* __restrict__ soff,
                                                   const int* __restrict__ sorted,
                                                   const float* __restrict__ t,
                                                   const float* __restrict__ hin,
                                                   const float* __restrict__ Wr,
                                                   const float* __restrict__ b,
                                                   const float* __restrict__ inv,
                                                   float* __restrict__ out) {
    __shared__ float acc[BN];
    const int bkt = blockIdx.x;
    const int tid = threadIdx.x;
    if (tid < BN) acc[tid] = 0.f;  // BN==512
    __syncthreads();
    int beg = soff[bkt * 9], end = soff[bkt * 9 + 4];
    int c = (end - beg + 511) >> 9;
    int k = beg + tid * c;
    const int ke = min(k + c, end);
    int cur = -1;
    float a0 = 0.f;
    auto flush = [&]() { if (cur >= 0) atomicAdd(&acc[cur], a0); };
    auto edge = [&](int e, float q) {
        int d = e & 511;
        if (d != cur) { flush(); cur = d; a0 = 0.f; }
        a0 += q;
    };
    int kk = k;
    while (kk < ke && (kk & 3)) { int e = sorted[kk]; edge(e, t[e >> 9]); ++kk; }
    for (; kk + 7 < ke; kk += 8) {
        int4v ea = __builtin_nontemporal_load((const int4v*)(sorted + kk));
        int4v eb = __builtin_nontemporal_load((const int4v*)(sorted + kk + 4));
        float q0 = t[ea.x >> 9], q1 = t[ea.y >> 9], q2 = t[ea.z >> 9], q3 = t[ea.w >> 9];
        float q4 = t[eb.x >> 9], q5 = t[eb.y >> 9], q6 = t[eb.z >> 9], q7 = t[eb.w >> 9];
        edge(ea.x, q0); edge(ea.y, q1); edge(ea.z, q2); edge(ea.w, q3);
        edge(eb.x, q4); edge(eb.y, q5); edge(eb.z, q6); edge(eb.w, q7);
    }
    for (; kk + 3 < ke; kk += 4) {
        int4v e4 = __builtin_nontemporal_load((const int4v*)(sorted + kk));
        float q0 = t[e4.x >> 9], q1 = t[e4.y >> 9], q2 = t[e4.z >> 9], q3 = t[e4.w >> 9];
        edge(e4.x, q0); edge(e4.y, q1); edge(e4.z, q2); edge(e4.w, q3);
    }
    for (; kk < ke; ++kk) { int e = sorted[kk]; edge(e, t[e >> 9]); }
    flush();
    __syncthreads();
    int node = bkt * BN + tid;
    if (node >= NN) return;
    float v = acc[tid] * inv[node] + b[0];
#pragma unroll
    for (int kq = 0; kq < 5; ++kq) v += hin[(size_t)node * 5 + kq] * Wr[kq];
    out[node] = v;
}

extern "C" void kernel_launch(void* const* d_in, const int* in_sizes, int n_in,
                              void* d_out, int out_size, void* d_ws, size_t ws_size,
                              hipStream_t stream) {
    (void)in_sizes; (void)n_in; (void)out_size; (void)ws_size;
    const float* x    = (const float*)d_in[0];
    const int*   ei   = (const int*)d_in[1];
    const float* Wl1  = (const float*)d_in[2];
    const float* Wr1  = (const float*)d_in[3];
    const float* b1   = (const float*)d_in[4];
    const float* Wlm  = (const float*)d_in[5];
    const float* Wrm  = (const float*)d_in[6];
    const float* bm   = (const float*)d_in[7];
    const float* Wl10 = (const float*)d_in[8];
    const float* Wr10 = (const float*)d_in[9];
    const float* b10  = (const float*)d_in[10];
    float* out = (float*)d_out;

    const int* src = ei;
    const int* dst = ei + NE;

    // workspace layout (4-byte units)
    int* wsI = (int*)d_ws;
    int*   gcnt    = wsI;                         // 977 -> pad 1024
    int*   soff    = wsI + 1024;                  // 977*9 used at stride 9 (5 live)
    int*   sortedB = wsI + 10240;                 // 977*17408 = 17,007,616
    float* inv     = (float*)(wsI + 17017856);    // 500,224
    int*   storeA  = wsI + 20019200;              // 17,007,616 (dead after passB)
    // feature tables alias the dead storeA region (9.5M ints < 17M):
    uint4* tA = (uint4*)(wsI + 20019200);         // NN uint4 = 2,000,000 ints (16B-aligned)
    uint4* tB = (uint4*)(wsI + 22019200);         // 2,000,000 ints
    float* tP = (float*)(wsI + 24019200);         // 500,224 (final-layer fp32 plane)
    float* hA = (float*)(wsI + 24519424);         // 2,500,608
    float* hB = (float*)(wsI + 27020032);         // 2,500,608 -> end 29,520,640

    dim3 gb(NBUCK);
    dim3 tb(512);

    // ---- build: two-pass (dst-bucket, then (pair,dst,parity) sort) ----
    hipMemsetAsync(gcnt, 0, 1024 * sizeof(int), stream);
    passA<<<dim3(NTILE_A), dim3(1024), 0, stream>>>(src, dst, gcnt, storeA);
    passB<<<gb, tb, 0, stream>>>(gcnt, storeA, sortedB, inv, soff);

    // ---- layer 1 (10 -> 5) ----  (transform0 overwrites storeA AFTER passB)
    transform0<<<dim3(NB_NODE), dim3(256), 0, stream>>>(x, Wl1, tA);
    layer_fused<10, 5><<<gb, tb, 0, stream>>>(soff, sortedB, tA,
                                              x, Wr1, b1, Wlm, inv, hA, tB, nullptr);

    // ---- middle layers 0..6 (5 -> 5) ----
    const uint4* tcur = tB; uint4* tnxt = tA;
    const float* hcur = hA; float* hnext = hB;
    for (int mi = 0; mi < 7; ++mi) {
        layer_fused<5, 5><<<gb, tb, 0, stream>>>(soff, sortedB, tcur,
                                                 hcur, Wrm + mi * 25, bm + mi * 5,
                                                 Wlm + (mi + 1) * 25, inv, hnext,
                                                 tnxt, nullptr);
        const uint4* tt = tcur; tcur = tnxt; tnxt = (uint4*)tt;
        const float* th = hcur; hcur = hnext; hnext = (float*)th;
    }
    // ---- middle layer 7: next pre-transform is final (5 -> 1) -> fp32 plane ----
    layer_fused<5, 1><<<gb, tb, 0, stream>>>(soff, sortedB, tcur,
                                             hcur, Wrm + 7 * 25, bm + 7 * 5,
                                             Wl10, inv, hnext, nullptr, tP);
    // ---- final layer (5 -> 1), no relu ----
    final_layer<<<gb, tb, 0, stream>>>(soff, sortedB, tP, hnext, Wr10, b10, inv, out);
}

// Round 12
// 1579.432 us; speedup vs baseline: 1.3491x; 1.1156x over previous
//
#include <hip/hip_runtime.h>

constexpr int NN = 500000;
constexpr int NE = 16000000;
constexpr int BN = 512;                       // dst nodes per bucket
constexpr int NBUCK = (NN + BN - 1) / BN;     // 977
constexpr int NSLICE = 8;                     // src slices of 65536 nodes
constexpr int NKEY = NSLICE * BN;             // 4096 sort bins per bucket
constexpr int CAPA = 17408;                   // per-bucket cap: mean 16384, +8 sigma
constexpr int TILE_A = 16384;                 // edges per pass-A tile (LDS-staged)
constexpr int NTILE_A = (NE + TILE_A - 1) / TILE_A; // 977
constexpr int NB_NODE = (NN + 255) / 256;     // 1954

typedef int int4v __attribute__((ext_vector_type(4)));

// ---------------- bf16 helpers ----------------
__device__ __forceinline__ unsigned bfr(float x) {   // fp32 -> bf16 bits (RNE)
    unsigned u = __float_as_uint(x);
    u += 0x7fffu + ((u >> 16) & 1u);
    return u >> 16;
}
__device__ __forceinline__ float bfl(unsigned u) { return __uint_as_float(u << 16); }
__device__ __forceinline__ float bfh(unsigned u) { return __uint_as_float(u & 0xffff0000u); }

// ---------------- pass A: LDS counting sort per tile, coalesced bucket write-out ----
// R1: scattered 4B stores -> 392 MB WRITE_SIZE. R4: fixed (passA out of top-5).
__global__ void __launch_bounds__(1024, 8) passA(const int* __restrict__ src,
                                                 const int* __restrict__ dst,
                                                 int* __restrict__ gcnt,
                                                 int* __restrict__ storeA) {
    __shared__ int hist[1024];    // per-bucket count (977 used)
    __shared__ int lbase[1024];   // local exclusive scan (bucket start in stage)
    __shared__ int lcur[1024];    // local scatter cursor
    __shared__ int gbase[1024];   // absolute base in storeA
    __shared__ int stage[TILE_A]; // 64 KB sorted tile
    const int tid = threadIdx.x;
    const int base = blockIdx.x * TILE_A;
    const int nt = min(TILE_A, NE - base);
    hist[tid] = 0;
    __syncthreads();
    for (int i = tid; i < nt; i += 1024)
        atomicAdd(&hist[dst[base + i] >> 9], 1);
    __syncthreads();
    const int cnt = hist[tid];
    lbase[tid] = cnt;
    __syncthreads();
    // inclusive Hillis-Steele scan over 1024 bins
    for (int off = 1; off < 1024; off <<= 1) {
        int add = (tid >= off) ? lbase[tid - off] : 0;
        __syncthreads();
        lbase[tid] += add;
        __syncthreads();
    }
    const int lb = lbase[tid] - cnt;   // exclusive
    lcur[tid] = lb;
    if (tid < NBUCK && cnt > 0) {
        int g = atomicAdd(&gcnt[tid], cnt);
        gbase[tid] = tid * CAPA + g;
    }
    __syncthreads();
    lbase[tid] = lb;                   // publish exclusive base for write-out
    // scatter tile into LDS in bucket-sorted order
    for (int i = tid; i < nt; i += 1024) {
        int d = dst[base + i];
        int s = src[base + i];         // tile window L2-hot on re-read
        int p = atomicAdd(&lcur[d >> 9], 1);
        stage[p] = (s << 9) | (d & 511);
    }
    __syncthreads();
    // coalesced write-out: one bucket per wave iteration
    const int wid = tid >> 6, lane = tid & 63;
    for (int b = wid; b < NBUCK; b += 16) {
        int c = hist[b];
        if (c == 0) continue;
        int l0 = lbase[b];
        int g0 = gbase[b];
        int wl = min(c, (b + 1) * CAPA - g0);  // statistically never clips
        for (int j = lane; j < wl; j += 64)
            storeA[g0 + j] = stage[l0 + j];
    }
}

// ---------------- pass B: per-bucket sort by (PAIR, dst, slice-parity) ----------------
// R11 confirmed: (pair,dst,parity) key (~8-edge runs) + 4x2MB phases = best
// sweep config (155 us vs 174/196 for short-run variants).
// key(e): pair = e>>26, parity = (e>>25)&1, dst = e&511.
__global__ void __launch_bounds__(512) passB(const int* __restrict__ gcnt,
                                             const int* __restrict__ storeA,
                                             int* __restrict__ sortedB,
                                             float* __restrict__ inv,
                                             int* __restrict__ soff) {
    __shared__ int hist[NKEY];    // 16 KB: counts, then (after scan) scatter cursors
    __shared__ int sc[512];       // 2 KB
    __shared__ int stage[CAPA];   // 68 KB sorted bucket
    const int bkt = blockIdx.x;
    const int tid = threadIdx.x;
#pragma unroll
    for (int u = 0; u < NKEY / 512; ++u) hist[tid + u * 512] = 0;
    __syncthreads();
    const int n = min(gcnt[bkt], CAPA);
    const int* bs = storeA + (size_t)bkt * CAPA;
    // histogram (dwordx4 reads; bs is 16B-aligned, tail scalar)
    const int n4 = n & ~3;
    for (int k = tid * 4; k < n4; k += 2048) {
        int4v e4 = *(const int4v*)(bs + k);
#pragma unroll
        for (int u = 0; u < 4; ++u) {
            int e = e4[u];
            int key = ((e >> 26) << 10) | ((e & 511) << 1) | ((e >> 25) & 1);
            atomicAdd(&hist[key], 1);
        }
    }
    for (int k = n4 + tid; k < n; k += 512) {
        int e = bs[k];
        int key = ((e >> 26) << 10) | ((e & 511) << 1) | ((e >> 25) & 1);
        atomicAdd(&hist[key], 1);
    }
    __syncthreads();
    // inv[] from per-dst counts (sum over 4 pairs x 2 parities)
    {
        int node = bkt * BN + tid;
        if (node < NN) {
            int c = 0;
#pragma unroll
            for (int p = 0; p < 4; ++p)
#pragma unroll
                for (int q = 0; q < 2; ++q)
                    c += hist[(p << 10) | (tid << 1) | q];
            inv[node] = 1.0f / fmaxf((float)c, 1.0f);
        }
    }
    // exclusive scan of 4096 bins: 8 bins per thread (hist dead after v[u] load)
    int v[NKEY / 512];
    int sum = 0;
#pragma unroll
    for (int u = 0; u < NKEY / 512; ++u) {
        v[u] = hist[tid * (NKEY / 512) + u];
        sum += v[u];
    }
    sc[tid] = sum;
    __syncthreads();
    for (int off = 1; off < 512; off <<= 1) {
        int add = (tid >= off) ? sc[tid - off] : 0;
        __syncthreads();
        sc[tid] += add;
        __syncthreads();
    }
    int run = sc[tid] - sum;           // LOCAL exclusive offset within bucket
    // pair start offsets (absolute): bin p<<10 is the first bin of thread p*128
    if ((tid & 127) == 0) soff[bkt * 9 + (tid >> 7)] = bkt * CAPA + run;
    if (tid == 511) soff[bkt * 9 + 4] = bkt * CAPA + n;
    // overwrite own hist bins with local scatter cursors
#pragma unroll
    for (int u = 0; u < NKEY / 512; ++u) {
        hist[tid * (NKEY / 512) + u] = run;
        run += v[u];
    }
    __syncthreads();
    // scatter into LDS stage (local positions)
    for (int k = tid * 4; k < n4; k += 2048) {
        int4v e4 = *(const int4v*)(bs + k);
#pragma unroll
        for (int u = 0; u < 4; ++u) {
            int e = e4[u];
            int key = ((e >> 26) << 10) | ((e & 511) << 1) | ((e >> 25) & 1);
            int p = atomicAdd(&hist[key], 1);
            stage[p] = e;
        }
    }
    for (int k = n4 + tid; k < n; k += 512) {
        int e = bs[k];
        int key = ((e >> 26) << 10) | ((e & 511) << 1) | ((e >> 25) & 1);
        int p = atomicAdd(&hist[key], 1);
        stage[p] = e;
    }
    __syncthreads();
    // contiguous, vectorized write-out: full lines, temporally clustered
    int* ob = sortedB + (size_t)bkt * CAPA;
    for (int k = tid * 4; k < n4; k += 2048)
        *(int4v*)(ob + k) = *(const int4v*)(stage + k);
    for (int k = n4 + tid; k < n; k += 512)
        ob[k] = stage[k];
}

// ---------------- layer-1 pre-transform: x @ Wl1.T (10 -> 5), bf16x5 packed in 16 B ----------------
__global__ void __launch_bounds__(256) transform0(const float* __restrict__ x,
                                                  const float* __restrict__ Wl1,
                                                  uint4* __restrict__ t16) {
    int i = blockIdx.x * 256 + threadIdx.x;
    if (i >= NN) return;
    float xi[10];
#pragma unroll
    for (int k = 0; k < 10; ++k) xi[k] = x[i * 10 + k];
    float v[5];
#pragma unroll
    for (int j = 0; j < 5; ++j) {
        float a = 0.f;
#pragma unroll
        for (int k = 0; k < 10; ++k) a += xi[k] * Wl1[j * 10 + k];
        v[j] = a;
    }
    uint4 w;
    w.x = bfr(v[0]) | (bfr(v[1]) << 16);
    w.y = bfr(v[2]) | (bfr(v[3]) << 16);
    w.z = bfr(v[4]);
    w.w = 0;
    t16[i] = w;
}

// ---------------- core: process LDS-resident edge range, register acc, flush on dst change ----
// R11 lesson: sweep is latency-duty-cycle bound; the chained global edge-load
// (~400-900cy) ahead of each gather was half the critical path. Edges now come
// from LDS (~120cy ds_read) — eds points into __shared__, inlining lets the
// compiler emit ds_read_b128 for the int4v loads.
__device__ __forceinline__ void process_range5_lds(const int* eds,
                                                   int k, const int ke,
                                                   const uint4* __restrict__ t16,
                                                   float* __restrict__ acc) {
    int cur = -1;
    float a0 = 0, a1 = 0, a2 = 0, a3 = 0, a4 = 0;
    auto flush = [&]() {
        if (cur >= 0) {
            float* p = &acc[cur * 5];
            atomicAdd(p + 0, a0); atomicAdd(p + 1, a1); atomicAdd(p + 2, a2);
            atomicAdd(p + 3, a3); atomicAdd(p + 4, a4);
        }
    };
    auto edge = [&](int e, uint4 w) {
        int d = e & 511;
        if (d != cur) { flush(); cur = d; a0 = a1 = a2 = a3 = a4 = 0.f; }
        a0 += bfl(w.x); a1 += bfh(w.x); a2 += bfl(w.y); a3 += bfh(w.y); a4 += bfl(w.z);
    };
    // scalar prologue: align k to 16 B (eds base is 16B-aligned)
    while (k < ke && (k & 3)) {
        int e = eds[k];
        edge(e, t16[e >> 9]);
        ++k;
    }
    // 8-wide main loop: 8 gathers in flight
    for (; k + 7 < ke; k += 8) {
        int4v ea = *(const int4v*)(eds + k);
        int4v eb = *(const int4v*)(eds + k + 4);
        uint4 w0 = t16[ea.x >> 9];
        uint4 w1 = t16[ea.y >> 9];
        uint4 w2 = t16[ea.z >> 9];
        uint4 w3 = t16[ea.w >> 9];
        uint4 w4 = t16[eb.x >> 9];
        uint4 w5 = t16[eb.y >> 9];
        uint4 w6 = t16[eb.z >> 9];
        uint4 w7 = t16[eb.w >> 9];
        edge(ea.x, w0); edge(ea.y, w1); edge(ea.z, w2); edge(ea.w, w3);
        edge(eb.x, w4); edge(eb.y, w5); edge(eb.z, w6); edge(eb.w, w7);
    }
    // 4-wide cleanup
    for (; k + 3 < ke; k += 4) {
        int4v e4 = *(const int4v*)(eds + k);
        uint4 w0 = t16[e4.x >> 9];
        uint4 w1 = t16[e4.y >> 9];
        uint4 w2 = t16[e4.z >> 9];
        uint4 w3 = t16[e4.w >> 9];
        edge(e4.x, w0); edge(e4.y, w1); edge(e4.z, w2); edge(e4.w, w3);
    }
    for (; k < ke; ++k) {
        int e = eds[k];
        edge(e, t16[e >> 9]);
    }
    flush();
}

// ---------------- fused layer: LDS-staged edges, 4 pair-phases, node update + next pre-transform ----
// Stage the bucket's whole edge array (<=68 KB) into LDS once (coalesced
// nontemporal stream, pure BW, off the critical chain), then all phases read
// edges via ds_read. LDS 78 KB -> 2 blocks/CU (~= measured 17 waves/CU, no
// TLP loss). Phase chain: ds_read(120cy)+gather(430cy) vs global(500+)+gather.
template <int FIN, int FNEXT>
__global__ void __launch_bounds__(512, 4) layer_fused(const int* __restrict__ soff,
                                                      const int* __restrict__ sorted,
                                                      const uint4* __restrict__ t16,
                                                      const float* __restrict__ hin,
                                                      const float* __restrict__ Wr,
                                                      const float* __restrict__ b,
                                                      const float* __restrict__ Wln,
                                                      const float* __restrict__ inv,
                                                      float* __restrict__ hout,
                                                      uint4* __restrict__ tn16,
                                                      float* __restrict__ tnP) {
    __shared__ float acc[BN * 5];   // 10 KB
    __shared__ int eds[CAPA];       // 68 KB
    const int bkt = blockIdx.x;
    const int tid = threadIdx.x;
    const int base = bkt * CAPA;
    const int n = soff[bkt * 9 + 4] - base;
    for (int k = tid; k < BN * 5; k += 512) acc[k] = 0.f;
    // stage edges: coalesced nontemporal dwordx4 stream into LDS
    const int n4 = n & ~3;
    for (int k = tid * 4; k < n4; k += 2048)
        *(int4v*)(eds + k) = __builtin_nontemporal_load((const int4v*)(sorted + base + k));
    for (int k = n4 + tid; k < n; k += 512)
        eds[k] = sorted[base + k];
    __syncthreads();
#pragma unroll
    for (int p = 0; p < 4; ++p) {
        int beg = soff[bkt * 9 + p] - base, end = soff[bkt * 9 + p + 1] - base;
        int c = (end - beg + 511) >> 9;
        int k = beg + tid * c;
        int ke = min(k + c, end);
        if (k < ke) process_range5_lds(eds, k, ke, t16, acc);
        __syncthreads();
    }

    int node = bkt * BN + tid;
    if (node >= NN) return;
    float iv = inv[node];
    float vin[FIN];
#pragma unroll
    for (int kk = 0; kk < FIN; ++kk) vin[kk] = hin[(size_t)node * FIN + kk];
    float ho[5];
#pragma unroll
    for (int jo = 0; jo < 5; ++jo) {
        float v = acc[tid * 5 + jo] * iv + b[jo];
#pragma unroll
        for (int kk = 0; kk < FIN; ++kk) v += vin[kk] * Wr[jo * FIN + kk];
        v = fmaxf(v, 0.f);
        hout[(size_t)node * 5 + jo] = v;
        ho[jo] = v;
    }
    if constexpr (FNEXT == 5) {
        float tv[5];
#pragma unroll
        for (int j2 = 0; j2 < 5; ++j2) {
            float v = 0.f;
#pragma unroll
            for (int jo = 0; jo < 5; ++jo) v += ho[jo] * Wln[j2 * 5 + jo];
            tv[j2] = v;
        }
        uint4 w;
        w.x = bfr(tv[0]) | (bfr(tv[1]) << 16);
        w.y = bfr(tv[2]) | (bfr(tv[3]) << 16);
        w.z = bfr(tv[4]);
        w.w = 0;
        tn16[node] = w;
    } else {  // FNEXT == 1: fp32 stride-1 plane for the final layer
        float v = 0.f;
#pragma unroll
        for (int jo = 0; jo < 5; ++jo) v += ho[jo] * Wln[jo];
        tnP[node] = v;
    }
}

// ---------------- final layer (5 -> 1): LDS-staged edges, t is a 2 MB fp32 plane (L2-fits) ----
__global__ void __launch_bounds__(512, 4) final_layer(const int* __restrict__ soff,
                                                      const int* __restrict__ sorted,
                                                      const float* __restrict__ t,
                                                      const float* __restrict__ hin,
                                                      const float* __restrict__ Wr,
                                                      const float* __restrict__ b,
                                                      const float* __restrict__ inv,
                                                      float* __restrict__ out) {
    __shared__ float acc[BN];       // 2 KB
    __shared__ int eds[CAPA];       // 68 KB
    const int bkt = blockIdx.x;
    const int tid = threadIdx.x;
    const int base = bkt * CAPA;
    const int n = soff[bkt * 9 + 4] - base;
    if (tid < BN) acc[tid] = 0.f;  // BN==512
    const int sn4 = n & ~3;
    for (int k = tid * 4; k < sn4; k += 2048)
        *(int4v*)(eds + k) = __builtin_nontemporal_load((const int4v*)(sorted + base + k));
    for (int k = sn4 + tid; k < n; k += 512)
        eds[k] = sorted[base + k];
    __syncthreads();
    int c = (n + 511) >> 9;
    int k = tid * c;
    const int ke = min(k + c, n);
    int cur = -1;
    float a0 = 0.f;
    auto flush = [&]() { if (cur >= 0) atomicAdd(&acc[cur], a0); };
    auto edge = [&](int e, float q) {
        int d = e & 511;
        if (d != cur) { flush(); cur = d; a0 = 0.f; }
        a0 += q;
    };
    int kk = k;
    while (kk < ke && (kk & 3)) { int e = eds[kk]; edge(e, t[e >> 9]); ++kk; }
    for (; kk + 7 < ke; kk += 8) {
        int4v ea = *(const int4v*)(eds + kk);
        int4v eb = *(const int4v*)(eds + kk + 4);
        float q0 = t[ea.x >> 9], q1 = t[ea.y >> 9], q2 = t[ea.z >> 9], q3 = t[ea.w >> 9];
        float q4 = t[eb.x >> 9], q5 = t[eb.y >> 9], q6 = t[eb.z >> 9], q7 = t[eb.w >> 9];
        edge(ea.x, q0); edge(ea.y, q1); edge(ea.z, q2); edge(ea.w, q3);
        edge(eb.x, q4); edge(eb.y, q5); edge(eb.z, q6); edge(eb.w, q7);
    }
    for (; kk + 3 < ke; kk += 4) {
        int4v e4 = *(const int4v*)(eds + kk);
        float q0 = t[e4.x >> 9], q1 = t[e4.y >> 9], q2 = t[e4.z >> 9], q3 = t[e4.w >> 9];
        edge(e4.x, q0); edge(e4.y, q1); edge(e4.z, q2); edge(e4.w, q3);
    }
    for (; kk < ke; ++kk) { int e = eds[kk]; edge(e, t[e >> 9]); }
    flush();
    __syncthreads();
    int node = bkt * BN + tid;
    if (node >= NN) return;
    float v = acc[tid] * inv[node] + b[0];
#pragma unroll
    for (int kq = 0; kq < 5; ++kq) v += hin[(size_t)node * 5 + kq] * Wr[kq];
    out[node] = v;
}

extern "C" void kernel_launch(void* const* d_in, const int* in_sizes, int n_in,
                              void* d_out, int out_size, void* d_ws, size_t ws_size,
                              hipStream_t stream) {
    (void)in_sizes; (void)n_in; (void)out_size; (void)ws_size;
    const float* x    = (const float*)d_in[0];
    const int*   ei   = (const int*)d_in[1];
    const float* Wl1  = (const float*)d_in[2];
    const float* Wr1  = (const float*)d_in[3];
    const float* b1   = (const float*)d_in[4];
    const float* Wlm  = (const float*)d_in[5];
    const float* Wrm  = (const float*)d_in[6];
    const float* bm   = (const float*)d_in[7];
    const float* Wl10 = (const float*)d_in[8];
    const float* Wr10 = (const float*)d_in[9];
    const float* b10  = (const float*)d_in[10];
    float* out = (float*)d_out;

    const int* src = ei;
    const int* dst = ei + NE;

    // workspace layout (4-byte units)
    int* wsI = (int*)d_ws;
    int*   gcnt    = wsI;                         // 977 -> pad 1024
    int*   soff    = wsI + 1024;                  // 977*9 used at stride 9 (5 live)
    int*   sortedB = wsI + 10240;                 // 977*17408 = 17,007,616
    float* inv     = (float*)(wsI + 17017856);    // 500,224
    int*   storeA  = wsI + 20019200;              // 17,007,616 (dead after passB)
    // feature tables alias the dead storeA region (9.5M ints < 17M):
    uint4* tA = (uint4*)(wsI + 20019200);         // NN uint4 = 2,000,000 ints (16B-aligned)
    uint4* tB = (uint4*)(wsI + 22019200);         // 2,000,000 ints
    float* tP = (float*)(wsI + 24019200);         // 500,224 (final-layer fp32 plane)
    float* hA = (float*)(wsI + 24519424);         // 2,500,608
    float* hB = (float*)(wsI + 27020032);         // 2,500,608 -> end 29,520,640

    dim3 gb(NBUCK);
    dim3 tb(512);

    // ---- build: two-pass (dst-bucket, then (pair,dst,parity) sort) ----
    hipMemsetAsync(gcnt, 0, 1024 * sizeof(int), stream);
    passA<<<dim3(NTILE_A), dim3(1024), 0, stream>>>(src, dst, gcnt, storeA);
    passB<<<gb, tb, 0, stream>>>(gcnt, storeA, sortedB, inv, soff);

    // ---- layer 1 (10 -> 5) ----  (transform0 overwrites storeA AFTER passB)
    transform0<<<dim3(NB_NODE), dim3(256), 0, stream>>>(x, Wl1, tA);
    layer_fused<10, 5><<<gb, tb, 0, stream>>>(soff, sortedB, tA,
                                              x, Wr1, b1, Wlm, inv, hA, tB, nullptr);

    // ---- middle layers 0..6 (5 -> 5) ----
    const uint4* tcur = tB; uint4* tnxt = tA;
    const float* hcur = hA; float* hnext = hB;
    for (int mi = 0; mi < 7; ++mi) {
        layer_fused<5, 5><<<gb, tb, 0, stream>>>(soff, sortedB, tcur,
                                                 hcur, Wrm + mi * 25, bm + mi * 5,
                                                 Wlm + (mi + 1) * 25, inv, hnext,
                                                 tnxt, nullptr);
        const uint4* tt = tcur; tcur = tnxt; tnxt = (uint4*)tt;
        const float* th = hcur; hcur = hnext; hnext = (float*)th;
    }
    // ---- middle layer 7: next pre-transform is final (5 -> 1) -> fp32 plane ----
    layer_fused<5, 1><<<gb, tb, 0, stream>>>(soff, sortedB, tcur,
                                             hcur, Wrm + 7 * 25, bm + 7 * 5,
                                             Wl10, inv, hnext, nullptr, tP);
    // ---- final layer (5 -> 1), no relu ----
    final_layer<<<gb, tb, 0, stream>>>(soff, sortedB, tP, hnext, Wr10, b10, inv, out);
}

// Round 14
// 1557.564 us; speedup vs baseline: 1.3681x; 1.0140x over previous
//
#include <hip/hip_runtime.h>

constexpr int NN = 500000;
constexpr int NE = 16000000;
constexpr int BN = 512;                       // dst nodes per bucket
constexpr int NBUCK = (NN + BN - 1) / BN;     // 977
constexpr int NSLICE = 8;                     // src slices of 65536 nodes
constexpr int NKEY = NSLICE * BN;             // 4096 sort bins per bucket
constexpr int CAPA = 17408;                   // per-bucket cap: mean 16384, +8 sigma
constexpr int PAIR_CAP = 5120;                // per-pair cap: mean 4094, +16 sigma
constexpr int TILE_A = 16384;                 // edges per pass-A tile (LDS-staged)
constexpr int NTILE_A = (NE + TILE_A - 1) / TILE_A; // 977
constexpr int NB_NODE = (NN + 255) / 256;     // 1954

typedef int int4v __attribute__((ext_vector_type(4)));

// ---------------- bf16 helpers ----------------
__device__ __forceinline__ unsigned bfr(float x) {   // fp32 -> bf16 bits (RNE)
    unsigned u = __float_as_uint(x);
    u += 0x7fffu + ((u >> 16) & 1u);
    return u >> 16;
}
__device__ __forceinline__ float bfl(unsigned u) { return __uint_as_float(u << 16); }
__device__ __forceinline__ float bfh(unsigned u) { return __uint_as_float(u & 0xffff0000u); }

// ---------------- pass A: LDS counting sort per tile, coalesced bucket write-out ----
// R1: scattered 4B stores -> 392 MB WRITE_SIZE. R4: fixed (passA out of top-5).
__global__ void __launch_bounds__(1024, 8) passA(const int* __restrict__ src,
                                                 const int* __restrict__ dst,
                                                 int* __restrict__ gcnt,
                                                 int* __restrict__ storeA) {
    __shared__ int hist[1024];    // per-bucket count (977 used)
    __shared__ int lbase[1024];   // local exclusive scan (bucket start in stage)
    __shared__ int lcur[1024];    // local scatter cursor
    __shared__ int gbase[1024];   // absolute base in storeA
    __shared__ int stage[TILE_A]; // 64 KB sorted tile
    const int tid = threadIdx.x;
    const int base = blockIdx.x * TILE_A;
    const int nt = min(TILE_A, NE - base);
    hist[tid] = 0;
    __syncthreads();
    for (int i = tid; i < nt; i += 1024)
        atomicAdd(&hist[dst[base + i] >> 9], 1);
    __syncthreads();
    const int cnt = hist[tid];
    lbase[tid] = cnt;
    __syncthreads();
    // inclusive Hillis-Steele scan over 1024 bins
    for (int off = 1; off < 1024; off <<= 1) {
        int add = (tid >= off) ? lbase[tid - off] : 0;
        __syncthreads();
        lbase[tid] += add;
        __syncthreads();
    }
    const int lb = lbase[tid] - cnt;   // exclusive
    lcur[tid] = lb;
    if (tid < NBUCK && cnt > 0) {
        int g = atomicAdd(&gcnt[tid], cnt);
        gbase[tid] = tid * CAPA + g;
    }
    __syncthreads();
    lbase[tid] = lb;                   // publish exclusive base for write-out
    // scatter tile into LDS in bucket-sorted order
    for (int i = tid; i < nt; i += 1024) {
        int d = dst[base + i];
        int s = src[base + i];         // tile window L2-hot on re-read
        int p = atomicAdd(&lcur[d >> 9], 1);
        stage[p] = (s << 9) | (d & 511);
    }
    __syncthreads();
    // coalesced write-out: one bucket per wave iteration
    const int wid = tid >> 6, lane = tid & 63;
    for (int b = wid; b < NBUCK; b += 16) {
        int c = hist[b];
        if (c == 0) continue;
        int l0 = lbase[b];
        int g0 = gbase[b];
        int wl = min(c, (b + 1) * CAPA - g0);  // statistically never clips
        for (int j = lane; j < wl; j += 64)
            storeA[g0 + j] = stage[l0 + j];
    }
}

// ---------------- pass B: per-bucket sort by (PAIR, dst, slice-parity) ----------------
// R11 confirmed: (pair,dst,parity) key (~8-edge runs) + pair-phases = best.
// key(e): pair = e>>26, parity = (e>>25)&1, dst = e&511.
__global__ void __launch_bounds__(512) passB(const int* __restrict__ gcnt,
                                             const int* __restrict__ storeA,
                                             int* __restrict__ sortedB,
                                             float* __restrict__ inv,
                                             int* __restrict__ soff) {
    __shared__ int hist[NKEY];    // 16 KB: counts, then (after scan) scatter cursors
    __shared__ int sc[512];       // 2 KB
    __shared__ int stage[CAPA];   // 68 KB sorted bucket
    const int bkt = blockIdx.x;
    const int tid = threadIdx.x;
#pragma unroll
    for (int u = 0; u < NKEY / 512; ++u) hist[tid + u * 512] = 0;
    __syncthreads();
    const int n = min(gcnt[bkt], CAPA);
    const int* bs = storeA + (size_t)bkt * CAPA;
    // histogram (dwordx4 reads; bs is 16B-aligned, tail scalar)
    const int n4 = n & ~3;
    for (int k = tid * 4; k < n4; k += 2048) {
        int4v e4 = *(const int4v*)(bs + k);
#pragma unroll
        for (int u = 0; u < 4; ++u) {
            int e = e4[u];
            int key = ((e >> 26) << 10) | ((e & 511) << 1) | ((e >> 25) & 1);
            atomicAdd(&hist[key], 1);
        }
    }
    for (int k = n4 + tid; k < n; k += 512) {
        int e = bs[k];
        int key = ((e >> 26) << 10) | ((e & 511) << 1) | ((e >> 25) & 1);
        atomicAdd(&hist[key], 1);
    }
    __syncthreads();
    // inv[] from per-dst counts (sum over 4 pairs x 2 parities)
    {
        int node = bkt * BN + tid;
        if (node < NN) {
            int c = 0;
#pragma unroll
            for (int p = 0; p < 4; ++p)
#pragma unroll
                for (int q = 0; q < 2; ++q)
                    c += hist[(p << 10) | (tid << 1) | q];
            inv[node] = 1.0f / fmaxf((float)c, 1.0f);
        }
    }
    // exclusive scan of 4096 bins: 8 bins per thread (hist dead after v[u] load)
    int v[NKEY / 512];
    int sum = 0;
#pragma unroll
    for (int u = 0; u < NKEY / 512; ++u) {
        v[u] = hist[tid * (NKEY / 512) + u];
        sum += v[u];
    }
    sc[tid] = sum;
    __syncthreads();
    for (int off = 1; off < 512; off <<= 1) {
        int add = (tid >= off) ? sc[tid - off] : 0;
        __syncthreads();
        sc[tid] += add;
        __syncthreads();
    }
    int run = sc[tid] - sum;           // LOCAL exclusive offset within bucket
    // pair start offsets (absolute): bin p<<10 is the first bin of thread p*128
    if ((tid & 127) == 0) soff[bkt * 9 + (tid >> 7)] = bkt * CAPA + run;
    if (tid == 511) soff[bkt * 9 + 4] = bkt * CAPA + n;
    // overwrite own hist bins with local scatter cursors
#pragma unroll
    for (int u = 0; u < NKEY / 512; ++u) {
        hist[tid * (NKEY / 512) + u] = run;
        run += v[u];
    }
    __syncthreads();
    // scatter into LDS stage (local positions)
    for (int k = tid * 4; k < n4; k += 2048) {
        int4v e4 = *(const int4v*)(bs + k);
#pragma unroll
        for (int u = 0; u < 4; ++u) {
            int e = e4[u];
            int key = ((e >> 26) << 10) | ((e & 511) << 1) | ((e >> 25) & 1);
            int p = atomicAdd(&hist[key], 1);
            stage[p] = e;
        }
    }
    for (int k = n4 + tid; k < n; k += 512) {
        int e = bs[k];
        int key = ((e >> 26) << 10) | ((e & 511) << 1) | ((e >> 25) & 1);
        int p = atomicAdd(&hist[key], 1);
        stage[p] = e;
    }
    __syncthreads();
    // contiguous, vectorized write-out: full lines, temporally clustered
    int* ob = sortedB + (size_t)bkt * CAPA;
    for (int k = tid * 4; k < n4; k += 2048)
        *(int4v*)(ob + k) = *(const int4v*)(stage + k);
    for (int k = n4 + tid; k < n; k += 512)
        ob[k] = stage[k];
}

// ---------------- layer-1 pre-transform: x @ Wl1.T (10 -> 5), bf16x5 packed in 16 B ----------------
__global__ void __launch_bounds__(256) transform0(const float* __restrict__ x,
                                                  const float* __restrict__ Wl1,
                                                  uint4* __restrict__ t16) {
    int i = blockIdx.x * 256 + threadIdx.x;
    if (i >= NN) return;
    float xi[10];
#pragma unroll
    for (int k = 0; k < 10; ++k) xi[k] = x[i * 10 + k];
    float v[5];
#pragma unroll
    for (int j = 0; j < 5; ++j) {
        float a = 0.f;
#pragma unroll
        for (int k = 0; k < 10; ++k) a += xi[k] * Wl1[j * 10 + k];
        v[j] = a;
    }
    uint4 w;
    w.x = bfr(v[0]) | (bfr(v[1]) << 16);
    w.y = bfr(v[2]) | (bfr(v[3]) << 16);
    w.z = bfr(v[4]);
    w.w = 0;
    t16[i] = w;
}

// ---------------- core: process LDS-resident edge range, register acc, flush on dst change ----
// 4-wide loop (R11: 8-wide neutral at ~8-edge runs; 4-wide keeps VGPR <= 64
// so 8 waves/EU fits). Edges from LDS (~120cy), gathers from L2 (~200cy).
__device__ __forceinline__ void process_range5_lds(const int* eds,
                                                   int k, const int ke,
                                                   const uint4* __restrict__ t16,
                                                   float* __restrict__ acc) {
    int cur = -1;
    float a0 = 0, a1 = 0, a2 = 0, a3 = 0, a4 = 0;
    auto flush = [&]() {
        if (cur >= 0) {
            float* p = &acc[cur * 5];
            atomicAdd(p + 0, a0); atomicAdd(p + 1, a1); atomicAdd(p + 2, a2);
            atomicAdd(p + 3, a3); atomicAdd(p + 4, a4);
        }
    };
    auto edge = [&](int e, uint4 w) {
        int d = e & 511;
        if (d != cur) { flush(); cur = d; a0 = a1 = a2 = a3 = a4 = 0.f; }
        a0 += bfl(w.x); a1 += bfh(w.x); a2 += bfl(w.y); a3 += bfh(w.y); a4 += bfl(w.z);
    };
    // scalar prologue: align k to 16 B (eds[i] == sorted[beg+i], bases aligned)
    while (k < ke && (k & 3)) {
        int e = eds[k];
        edge(e, t16[e >> 9]);
        ++k;
    }
    for (; k + 3 < ke; k += 4) {
        int4v e4 = *(const int4v*)(eds + k);
        uint4 w0 = t16[e4.x >> 9];
        uint4 w1 = t16[e4.y >> 9];
        uint4 w2 = t16[e4.z >> 9];
        uint4 w3 = t16[e4.w >> 9];
        edge(e4.x, w0); edge(e4.y, w1); edge(e4.z, w2); edge(e4.w, w3);
    }
    for (; k < ke; ++k) {
        int e = eds[k];
        edge(e, t16[e >> 9]);
    }
    flush();
}

// ---------------- fused layer: per-PAIR LDS staging -> 4 blocks/CU ----------------
// R12 counters: full-bucket staging (78 KB LDS) -> 2 blocks/CU, occupancy 39.6%,
// waves stalled ~85% -> outstanding-gather CONCURRENCY is the binding limit
// (every rate floor is 26-30us vs 137 measured). Stage one pair (<=20 KB) at a
// time: LDS 30 KB -> 4 blocks/CU = 32 waves (100%). Stage waits overlap across
// the 4 co-resident blocks.
template <int FIN, int FNEXT>
__global__ void __launch_bounds__(512, 8) layer_fused(const int* __restrict__ soff,
                                                      const int* __restrict__ sorted,
                                                      const uint4* __restrict__ t16,
                                                      const float* __restrict__ hin,
                                                      const float* __restrict__ Wr,
                                                      const float* __restrict__ b,
                                                      const float* __restrict__ Wln,
                                                      const float* __restrict__ inv,
                                                      float* __restrict__ hout,
                                                      uint4* __restrict__ tn16,
                                                      float* __restrict__ tnP) {
    __shared__ float acc[BN * 5];   // 10 KB
    __shared__ int eds[PAIR_CAP];   // 20 KB
    const int bkt = blockIdx.x;
    const int tid = threadIdx.x;
    for (int k = tid; k < BN * 5; k += 512) acc[k] = 0.f;
#pragma unroll
    for (int p = 0; p < 4; ++p) {
        const int beg = soff[bkt * 9 + p];
        const int n = min(soff[bkt * 9 + p + 1] - beg, PAIR_CAP);
        // stage this pair's edges (coalesced dword stream; beg not 16B-aligned)
#pragma unroll 4
        for (int k = tid; k < n; k += 512)
            eds[k] = __builtin_nontemporal_load(sorted + beg + k);
        __syncthreads();
        const int c = (n + 511) >> 9;
        const int k = tid * c;
        const int ke = min(k + c, n);
        if (k < ke) process_range5_lds(eds, k, ke, t16, acc);
        __syncthreads();
    }

    int node = bkt * BN + tid;
    if (node >= NN) return;
    float iv = inv[node];
    float vin[FIN];
#pragma unroll
    for (int kk = 0; kk < FIN; ++kk) vin[kk] = hin[(size_t)node * FIN + kk];
    float ho[5];
#pragma unroll
    for (int jo = 0; jo < 5; ++jo) {
        float v = acc[tid * 5 + jo] * iv + b[jo];
#pragma unroll
        for (int kk = 0; kk < FIN; ++kk) v += vin[kk] * Wr[jo * FIN + kk];
        v = fmaxf(v, 0.f);
        hout[(size_t)node * 5 + jo] = v;
        ho[jo] = v;
    }
    if constexpr (FNEXT == 5) {
        float tv[5];
#pragma unroll
        for (int j2 = 0; j2 < 5; ++j2) {
            float v = 0.f;
#pragma unroll
            for (int jo = 0; jo < 5; ++jo) v += ho[jo] * Wln[j2 * 5 + jo];
            tv[j2] = v;
        }
        uint4 w;
        w.x = bfr(tv[0]) | (bfr(tv[1]) << 16);
        w.y = bfr(tv[2]) | (bfr(tv[3]) << 16);
        w.z = bfr(tv[4]);
        w.w = 0;
        tn16[node] = w;
    } else {  // FNEXT == 1: fp32 stride-1 plane for the final layer
        float v = 0.f;
#pragma unroll
        for (int jo = 0; jo < 5; ++jo) v += ho[jo] * Wln[jo];
        tnP[node] = v;
    }
}

// ---------------- final layer (5 -> 1): LDS-staged edges, t is a 2 MB fp32 plane (L2-fits) ----
__global__ void __launch_bounds__(512, 4) final_layer(const int* __restrict__ soff,
                                                      const int* __restrict__ sorted,
                                                      const float* __restrict__ t,
                                                      const float* __restrict__ hin,
                                                      const float* __restrict__ Wr,
                                                      const float* __restrict__ b,
                                                      const float* __restrict__ inv,
                                                      float* __restrict__ out) {
    __shared__ float acc[BN];       // 2 KB
    __shared__ int eds[CAPA];       // 68 KB
    const int bkt = blockIdx.x;
    const int tid = threadIdx.x;
    const int base = bkt * CAPA;
    const int n = soff[bkt * 9 + 4] - base;
    if (tid < BN) acc[tid] = 0.f;  // BN==512
    const int sn4 = n & ~3;
    for (int k = tid * 4; k < sn4; k += 2048)
        *(int4v*)(eds + k) = __builtin_nontemporal_load((const int4v*)(sorted + base + k));
    for (int k = sn4 + tid; k < n; k += 512)
        eds[k] = sorted[base + k];
    __syncthreads();
    int c = (n + 511) >> 9;
    int k = tid * c;
    const int ke = min(k + c, n);
    int cur = -1;
    float a0 = 0.f;
    auto flush = [&]() { if (cur >= 0) atomicAdd(&acc[cur], a0); };
    auto edge = [&](int e, float q) {
        int d = e & 511;
        if (d != cur) { flush(); cur = d; a0 = 0.f; }
        a0 += q;
    };
    int kk = k;
    while (kk < ke && (kk & 3)) { int e = eds[kk]; edge(e, t[e >> 9]); ++kk; }
    for (; kk + 3 < ke; kk += 4) {
        int4v e4 = *(const int4v*)(eds + kk);
        float q0 = t[e4.x >> 9], q1 = t[e4.y >> 9], q2 = t[e4.z >> 9], q3 = t[e4.w >> 9];
        edge(e4.x, q0); edge(e4.y, q1); edge(e4.z, q2); edge(e4.w, q3);
    }
    for (; kk < ke; ++kk) { int e = eds[kk]; edge(e, t[e >> 9]); }
    flush();
    __syncthreads();
    int node = bkt * BN + tid;
    if (node >= NN) return;
    float v = acc[tid] * inv[node] + b[0];
#pragma unroll
    for (int kq = 0; kq < 5; ++kq) v += hin[(size_t)node * 5 + kq] * Wr[kq];
    out[node] = v;
}

extern "C" void kernel_launch(void* const* d_in, const int* in_sizes, int n_in,
                              void* d_out, int out_size, void* d_ws, size_t ws_size,
                              hipStream_t stream) {
    (void)in_sizes; (void)n_in; (void)out_size; (void)ws_size;
    const float* x    = (const float*)d_in[0];
    const int*   ei   = (const int*)d_in[1];
    const float* Wl1  = (const float*)d_in[2];
    const float* Wr1  = (const float*)d_in[3];
    const float* b1   = (const float*)d_in[4];
    const float* Wlm  = (const float*)d_in[5];
    const float* Wrm  = (const float*)d_in[6];
    const float* bm   = (const float*)d_in[7];
    const float* Wl10 = (const float*)d_in[8];
    const float* Wr10 = (const float*)d_in[9];
    const float* b10  = (const float*)d_in[10];
    float* out = (float*)d_out;

    const int* src = ei;
    const int* dst = ei + NE;

    // workspace layout (4-byte units)
    int* wsI = (int*)d_ws;
    int*   gcnt    = wsI;                         // 977 -> pad 1024
    int*   soff    = wsI + 1024;                  // 977*9 used at stride 9 (5 live)
    int*   sortedB = wsI + 10240;                 // 977*17408 = 17,007,616
    float* inv     = (float*)(wsI + 17017856);    // 500,224
    int*   storeA  = wsI + 20019200;              // 17,007,616 (dead after passB)
    // feature tables alias the dead storeA region (9.5M ints < 17M):
    uint4* tA = (uint4*)(wsI + 20019200);         // NN uint4 = 2,000,000 ints (16B-aligned)
    uint4* tB = (uint4*)(wsI + 22019200);         // 2,000,000 ints
    float* tP = (float*)(wsI + 24019200);         // 500,224 (final-layer fp32 plane)
    float* hA = (float*)(wsI + 24519424);         // 2,500,608
    float* hB = (float*)(wsI + 27020032);         // 2,500,608 -> end 29,520,640

    dim3 gb(NBUCK);
    dim3 tb(512);

    // ---- build: two-pass (dst-bucket, then (pair,dst,parity) sort) ----
    hipMemsetAsync(gcnt, 0, 1024 * sizeof(int), stream);
    passA<<<dim3(NTILE_A), dim3(1024), 0, stream>>>(src, dst, gcnt, storeA);
    passB<<<gb, tb, 0, stream>>>(gcnt, storeA, sortedB, inv, soff);

    // ---- layer 1 (10 -> 5) ----  (transform0 overwrites storeA AFTER passB)
    transform0<<<dim3(NB_NODE), dim3(256), 0, stream>>>(x, Wl1, tA);
    layer_fused<10, 5><<<gb, tb, 0, stream>>>(soff, sortedB, tA,
                                              x, Wr1, b1, Wlm, inv, hA, tB, nullptr);

    // ---- middle layers 0..6 (5 -> 5) ----
    const uint4* tcur = tB; uint4* tnxt = tA;
    const float* hcur = hA; float* hnext = hB;
    for (int mi = 0; mi < 7; ++mi) {
        layer_fused<5, 5><<<gb, tb, 0, stream>>>(soff, sortedB, tcur,
                                                 hcur, Wrm + mi * 25, bm + mi * 5,
                                                 Wlm + (mi + 1) * 25, inv, hnext,
                                                 tnxt, nullptr);
        const uint4* tt = tcur; tcur = tnxt; tnxt = (uint4*)tt;
        const float* th = hcur; hcur = hnext; hnext = (float*)th;
    }
    // ---- middle layer 7: next pre-transform is final (5 -> 1) -> fp32 plane ----
    layer_fused<5, 1><<<gb, tb, 0, stream>>>(soff, sortedB, tcur,
                                             hcur, Wrm + 7 * 25, bm + 7 * 5,
                                             Wl10, inv, hnext, nullptr, tP);
    // ---- final layer (5 -> 1), no relu ----
    final_layer<<<gb, tb, 0, stream>>>(soff, sortedB, tP, hnext, Wr10, b10, inv, out);
}